// Round 1
// baseline (1227.352 us; speedup 1.0000x reference)
//
#include <hip/hip_runtime.h>

#define N_NODES 100000
#define N_EDGES 640000
#define D 128

// ---------------------------------------------------------------- utilities
__global__ void zero_i32(int* __restrict__ p, int n) {
  int i = blockIdx.x * blockDim.x + threadIdx.x;
  if (i < n) p[i] = 0;
}

// ------------------------------------------------------------- CSR building
__global__ void hist_kernel(const int* __restrict__ dst, int* __restrict__ deg, int E) {
  int i = blockIdx.x * blockDim.x + threadIdx.x;
  if (i < E) atomicAdd(&deg[dst[i]], 1);
}

// single-block exclusive scan of deg[0..n) -> row_start[0..n]
__global__ void scan_kernel(const int* __restrict__ deg, int* __restrict__ row_start, int n) {
  __shared__ int lds[1024];
  const int tid = threadIdx.x;
  const int chunk = (n + 1023) >> 10;
  const int begin = min(tid * chunk, n);
  const int end = min(begin + chunk, n);
  int s = 0;
  for (int i = begin; i < end; ++i) s += deg[i];
  lds[tid] = s;
  __syncthreads();
  for (int off = 1; off < 1024; off <<= 1) {
    int v = (tid >= off) ? lds[tid - off] : 0;
    __syncthreads();
    lds[tid] += v;
    __syncthreads();
  }
  int prefix = (tid == 0) ? 0 : lds[tid - 1];
  for (int i = begin; i < end; ++i) { row_start[i] = prefix; prefix += deg[i]; }
  if (tid == 0) row_start[n] = lds[1023];
}

__global__ void fill_kernel(const int* __restrict__ src, const int* __restrict__ dst,
                            const int* __restrict__ row_start, int* __restrict__ cursor,
                            int* __restrict__ esrc, int E) {
  int i = blockIdx.x * blockDim.x + threadIdx.x;
  if (i < E) {
    int d = dst[i];
    int pos = atomicAdd(&cursor[d], 1);
    esrc[row_start[d] + pos] = src[i];
  }
}

// ----------------------------------------------------- mean aggregation
// one wave (64 lanes) per node; lane l owns features [2l, 2l+1]
__global__ void aggregate_kernel(const float* __restrict__ h, const int* __restrict__ row_start,
                                 const int* __restrict__ esrc, float* __restrict__ mean, int n) {
  int gid = blockIdx.x * blockDim.x + threadIdx.x;
  int node = gid >> 6;
  int lane = threadIdx.x & 63;
  if (node >= n) return;
  int s0 = row_start[node], s1 = row_start[node + 1];
  float2 acc = {0.f, 0.f};
  for (int e = s0; e < s1; ++e) {
    int s = esrc[e];
    float2 v = *(const float2*)(h + (size_t)s * D + lane * 2);
    acc.x += v.x;
    acc.y += v.y;
  }
  float inv = 1.0f / (float)max(s1 - s0, 1);
  acc.x *= inv;
  acc.y *= inv;
  *(float2*)(mean + (size_t)node * D + lane * 2) = acc;
}

// ----------------------------------------------------- dual-input fp32 GEMM
// out[M,128] = in0 @ W0 + (HAS2 ? in1 @ W1 : 0) + bias
// W row-major [128,128]; 64 rows per block, 256 threads, 4x8 acc/thread.
template <bool HAS2>
__global__ __launch_bounds__(256) void gemm_dual(
    const float* __restrict__ in0, const float* __restrict__ in1,
    const float* __restrict__ W0, const float* __restrict__ W1,
    const float* __restrict__ bias, float* __restrict__ out, int M) {
  __shared__ float aT[64][68];   // +4 pad breaks 4-way bank conflict on column reads
  __shared__ float wT[64][128];
  const int tid = threadIdx.x;
  const int m0 = blockIdx.x * 64;
  const int ty = tid >> 4, tx = tid & 15;
  const int ty4 = ty * 4, tx8 = tx * 8;
  float acc[4][8];
#pragma unroll
  for (int i = 0; i < 4; ++i)
#pragma unroll
    for (int j = 0; j < 8; ++j) acc[i][j] = 0.f;

  const int nch = HAS2 ? 4 : 2;
  for (int c = 0; c < nch; ++c) {
    const float* src = (c < 2) ? in0 : in1;
    const float* wsrc = (c < 2) ? W0 : W1;
    const int kb = (c & 1) * 64;
    // stage 64x64 input tile
#pragma unroll
    for (int it = 0; it < 4; ++it) {
      int lin = it * 256 + tid;
      int row = lin >> 4, k4 = (lin & 15) * 4;
      int gm = min(m0 + row, M - 1);
      *(float4*)&aT[row][k4] = *(const float4*)&src[(size_t)gm * D + kb + k4];
    }
    // stage 64x128 weight tile
#pragma unroll
    for (int it = 0; it < 8; ++it) {
      int lin = it * 256 + tid;
      int row = lin >> 5, c4 = (lin & 31) * 4;
      *(float4*)&wT[row][c4] = *(const float4*)&wsrc[(size_t)(kb + row) * D + c4];
    }
    __syncthreads();
#pragma unroll
    for (int k = 0; k < 64; k += 4) {
      float a[4][4];
#pragma unroll
      for (int i = 0; i < 4; ++i) *(float4*)&a[i][0] = *(const float4*)&aT[ty4 + i][k];
#pragma unroll
      for (int j = 0; j < 4; ++j) {
        float4 wlo = *(const float4*)&wT[k + j][tx8];
        float4 whi = *(const float4*)&wT[k + j][tx8 + 4];
#pragma unroll
        for (int i = 0; i < 4; ++i) {
          float av = a[i][j];
          acc[i][0] += av * wlo.x;
          acc[i][1] += av * wlo.y;
          acc[i][2] += av * wlo.z;
          acc[i][3] += av * wlo.w;
          acc[i][4] += av * whi.x;
          acc[i][5] += av * whi.y;
          acc[i][6] += av * whi.z;
          acc[i][7] += av * whi.w;
        }
      }
    }
    __syncthreads();
  }
  float b[8];
#pragma unroll
  for (int j = 0; j < 8; ++j) b[j] = bias ? bias[tx8 + j] : 0.f;
#pragma unroll
  for (int i = 0; i < 4; ++i) {
    int m = m0 + ty4 + i;
    if (m < M) {
      float4 lo = {acc[i][0] + b[0], acc[i][1] + b[1], acc[i][2] + b[2], acc[i][3] + b[3]};
      float4 hi = {acc[i][4] + b[4], acc[i][5] + b[5], acc[i][6] + b[6], acc[i][7] + b[7]};
      *(float4*)&out[(size_t)m * D + tx8] = lo;
      *(float4*)&out[(size_t)m * D + tx8 + 4] = hi;
    }
  }
}

// ----------------------------------------------------- per-edge MLP score
// score[e] = relu(A[s] + B[d]) . Wp2 + bp2   (bp1 folded into A)
// one wave per edge, lane l owns features [2l, 2l+1]
__global__ void edge_score_kernel(const float* __restrict__ A, const float* __restrict__ B,
                                  const int* __restrict__ s, const int* __restrict__ d,
                                  const float* __restrict__ Wp2, const float* __restrict__ bp2,
                                  float* __restrict__ out, int E) {
  int gid = blockIdx.x * blockDim.x + threadIdx.x;
  int e = gid >> 6;
  int lane = threadIdx.x & 63;
  if (e >= E) return;
  int si = s[e], di = d[e];
  float2 a = *(const float2*)(A + (size_t)si * D + lane * 2);
  float2 b = *(const float2*)(B + (size_t)di * D + lane * 2);
  float2 w = *(const float2*)(Wp2 + lane * 2);
  float x0 = a.x + b.x;
  float x1 = a.y + b.y;
  x0 = x0 > 0.f ? x0 : 0.f;
  x1 = x1 > 0.f ? x1 : 0.f;
  float p = x0 * w.x + x1 * w.y;
#pragma unroll
  for (int off = 32; off > 0; off >>= 1) p += __shfl_down(p, off);
  if (lane == 0) out[e] = p + bp2[0];
}

// ---------------------------------------------------------------- launcher
extern "C" void kernel_launch(void* const* d_in, const int* in_sizes, int n_in,
                              void* d_out, int out_size, void* d_ws, size_t ws_size,
                              hipStream_t stream) {
  const float* x = (const float*)d_in[0];
  const int* src = (const int*)d_in[1];
  const int* dst = (const int*)d_in[2];
  const int* nsrc = (const int*)d_in[3];
  const int* ndst = (const int*)d_in[4];
  const float* Ws1 = (const float*)d_in[5];
  const float* Wn1 = (const float*)d_in[6];
  const float* b1 = (const float*)d_in[7];
  const float* Ws2 = (const float*)d_in[8];
  const float* Wn2 = (const float*)d_in[9];
  const float* b2 = (const float*)d_in[10];
  const float* Ws3 = (const float*)d_in[11];
  const float* Wn3 = (const float*)d_in[12];
  const float* b3 = (const float*)d_in[13];
  const float* Wp1 = (const float*)d_in[14];
  const float* bp1 = (const float*)d_in[15];
  const float* Wp2 = (const float*)d_in[16];
  const float* bp2 = (const float*)d_in[17];
  float* out = (float*)d_out;

  char* ws = (char*)d_ws;
  size_t off = 0;
  auto alloc = [&](size_t bytes) -> void* {
    void* p = ws + off;
    off += (bytes + 255) & ~(size_t)255;
    return p;
  };
  float* buf0 = (float*)alloc(sizeof(float) * (size_t)N_NODES * D);
  float* buf1 = (float*)alloc(sizeof(float) * (size_t)N_NODES * D);
  float* buf2 = (float*)alloc(sizeof(float) * (size_t)N_NODES * D);
  int* row_start = (int*)alloc(sizeof(int) * (N_NODES + 1));
  int* deg = (int*)alloc(sizeof(int) * N_NODES * 2);  // deg + cursor contiguous
  int* cursor = deg + N_NODES;
  int* esrc = (int*)alloc(sizeof(int) * N_EDGES);
  (void)ws_size;

  // ---- CSR build (reused by all 3 layers)
  zero_i32<<<(2 * N_NODES + 255) / 256, 256, 0, stream>>>(deg, 2 * N_NODES);
  hist_kernel<<<(N_EDGES + 255) / 256, 256, 0, stream>>>(dst, deg, N_EDGES);
  scan_kernel<<<1, 1024, 0, stream>>>(deg, row_start, N_NODES);
  fill_kernel<<<(N_EDGES + 255) / 256, 256, 0, stream>>>(src, dst, row_start, cursor, esrc, N_EDGES);

  const int aggBlocks = (N_NODES + 3) / 4;     // 4 waves/block, 1 wave/node
  const int gemmBlocks = (N_NODES + 63) / 64;  // 64 rows/block

  // ---- layer 1: mean(x) -> buf0 ; h1 = x@Ws1 + mean@Wn1 + b1 -> buf1
  aggregate_kernel<<<aggBlocks, 256, 0, stream>>>(x, row_start, esrc, buf0, N_NODES);
  gemm_dual<true><<<gemmBlocks, 256, 0, stream>>>(x, buf0, Ws1, Wn1, b1, buf1, N_NODES);
  // ---- layer 2: h2 -> buf2
  aggregate_kernel<<<aggBlocks, 256, 0, stream>>>(buf1, row_start, esrc, buf0, N_NODES);
  gemm_dual<true><<<gemmBlocks, 256, 0, stream>>>(buf1, buf0, Ws2, Wn2, b2, buf2, N_NODES);
  // ---- layer 3: h3 -> buf1
  aggregate_kernel<<<aggBlocks, 256, 0, stream>>>(buf2, row_start, esrc, buf0, N_NODES);
  gemm_dual<true><<<gemmBlocks, 256, 0, stream>>>(buf2, buf0, Ws3, Wn3, b3, buf1, N_NODES);
  // ---- predictor precompute: A = h3@Wp1_top + bp1 -> buf0 ; B = h3@Wp1_bot -> buf2
  gemm_dual<false><<<gemmBlocks, 256, 0, stream>>>(buf1, nullptr, Wp1, nullptr, bp1, buf0, N_NODES);
  gemm_dual<false><<<gemmBlocks, 256, 0, stream>>>(buf1, nullptr, Wp1 + D * D, nullptr, nullptr, buf2, N_NODES);
  // ---- edge scores: pos then neg, concatenated in d_out
  edge_score_kernel<<<N_EDGES / 4, 256, 0, stream>>>(buf0, buf2, src, dst, Wp2, bp2, out, N_EDGES);
  edge_score_kernel<<<N_EDGES / 4, 256, 0, stream>>>(buf0, buf2, nsrc, ndst, Wp2, bp2, out + N_EDGES, N_EDGES);
}

// Round 2
// 1076.419 us; speedup vs baseline: 1.1402x; 1.1402x over previous
//
#include <hip/hip_runtime.h>

#define N_NODES 100000
#define N_EDGES 640000
#define D 128
#define SCAN_TILE 1024
#define SCAN_BLOCKS ((N_NODES + SCAN_TILE - 1) / SCAN_TILE)  // 98

// ---------------------------------------------------------------- utilities
__global__ void zero_i32(int* __restrict__ p, int n) {
  int i = blockIdx.x * blockDim.x + threadIdx.x;
  if (i < n) p[i] = 0;
}

// ------------------------------------------------------------- CSR building
__global__ void hist_kernel(const int* __restrict__ dst, int* __restrict__ deg, int E) {
  int i = blockIdx.x * blockDim.x + threadIdx.x;
  if (i < E) atomicAdd(&deg[dst[i]], 1);
}

// ---- hierarchical exclusive scan of deg[0..n) -> row_start[0..n] ----
// stage 1: per-block (1024 elems) sums
__global__ void scan_blocksum(const int* __restrict__ deg, int* __restrict__ partial, int n) {
  __shared__ int lds[256];
  const int tid = threadIdx.x;
  const int base = blockIdx.x * SCAN_TILE + tid * 4;
  int s = 0;
#pragma unroll
  for (int j = 0; j < 4; ++j) {
    int i = base + j;
    if (i < n) s += deg[i];
  }
  lds[tid] = s;
  __syncthreads();
  for (int off = 128; off > 0; off >>= 1) {
    if (tid < off) lds[tid] += lds[tid + off];
    __syncthreads();
  }
  if (tid == 0) partial[blockIdx.x] = lds[0];
}

// stage 2: single tiny block scans the partials in place (-> exclusive offsets),
// writes row_start[n] = grand total
__global__ void scan_offsets(int* __restrict__ partial, int* __restrict__ row_start, int nb, int n) {
  __shared__ int lds[128];
  const int tid = threadIdx.x;
  int v = (tid < nb) ? partial[tid] : 0;
  lds[tid] = v;
  __syncthreads();
  for (int off = 1; off < 128; off <<= 1) {
    int t = (tid >= off) ? lds[tid - off] : 0;
    __syncthreads();
    lds[tid] += t;
    __syncthreads();
  }
  if (tid < nb) partial[tid] = (tid == 0) ? 0 : lds[tid - 1];
  if (tid == 0) row_start[n] = lds[nb - 1];
}

// stage 3: per-block local exclusive scan + block offset -> row_start[0..n)
__global__ void scan_final(const int* __restrict__ deg, const int* __restrict__ partial,
                           int* __restrict__ row_start, int n) {
  __shared__ int lds[256];
  const int tid = threadIdx.x;
  const int base = blockIdx.x * SCAN_TILE + tid * 4;
  int d[4];
  int s = 0;
#pragma unroll
  for (int j = 0; j < 4; ++j) {
    int i = base + j;
    d[j] = (i < n) ? deg[i] : 0;
    s += d[j];
  }
  lds[tid] = s;
  __syncthreads();
  for (int off = 1; off < 256; off <<= 1) {
    int t = (tid >= off) ? lds[tid - off] : 0;
    __syncthreads();
    lds[tid] += t;
    __syncthreads();
  }
  int pre = partial[blockIdx.x] + lds[tid] - s;  // exclusive within block + block offset
#pragma unroll
  for (int j = 0; j < 4; ++j) {
    int i = base + j;
    if (i < n) {
      row_start[i] = pre;
      pre += d[j];
    }
  }
}

__global__ void fill_kernel(const int* __restrict__ src, const int* __restrict__ dst,
                            const int* __restrict__ row_start, int* __restrict__ cursor,
                            int* __restrict__ esrc, int E) {
  int i = blockIdx.x * blockDim.x + threadIdx.x;
  if (i < E) {
    int d = dst[i];
    int pos = atomicAdd(&cursor[d], 1);
    esrc[row_start[d] + pos] = src[i];
  }
}

// ----------------------------------------------------- mean aggregation
// one wave (64 lanes) per node; lane l owns features [2l, 2l+1]
__global__ void aggregate_kernel(const float* __restrict__ h, const int* __restrict__ row_start,
                                 const int* __restrict__ esrc, float* __restrict__ mean, int n) {
  int gid = blockIdx.x * blockDim.x + threadIdx.x;
  int node = gid >> 6;
  int lane = threadIdx.x & 63;
  if (node >= n) return;
  int s0 = row_start[node], s1 = row_start[node + 1];
  float2 acc = {0.f, 0.f};
  for (int e = s0; e < s1; ++e) {
    int s = esrc[e];
    float2 v = *(const float2*)(h + (size_t)s * D + lane * 2);
    acc.x += v.x;
    acc.y += v.y;
  }
  float inv = 1.0f / (float)max(s1 - s0, 1);
  acc.x *= inv;
  acc.y *= inv;
  *(float2*)(mean + (size_t)node * D + lane * 2) = acc;
}

// ----------------------------------------------------- dual-input fp32 GEMM
// out[M,128] = in0 @ W0 + (HAS2 ? in1 @ W1 : 0) + bias
// W row-major [128,128]; 64 rows per block, 256 threads, 4x8 acc/thread.
template <bool HAS2>
__global__ __launch_bounds__(256) void gemm_dual(
    const float* __restrict__ in0, const float* __restrict__ in1,
    const float* __restrict__ W0, const float* __restrict__ W1,
    const float* __restrict__ bias, float* __restrict__ out, int M) {
  __shared__ float aT[64][68];   // +4 pad breaks 4-way bank conflict on column reads
  __shared__ float wT[64][128];
  const int tid = threadIdx.x;
  const int m0 = blockIdx.x * 64;
  const int ty = tid >> 4, tx = tid & 15;
  const int ty4 = ty * 4, tx8 = tx * 8;
  float acc[4][8];
#pragma unroll
  for (int i = 0; i < 4; ++i)
#pragma unroll
    for (int j = 0; j < 8; ++j) acc[i][j] = 0.f;

  const int nch = HAS2 ? 4 : 2;
  for (int c = 0; c < nch; ++c) {
    const float* src = (c < 2) ? in0 : in1;
    const float* wsrc = (c < 2) ? W0 : W1;
    const int kb = (c & 1) * 64;
    // stage 64x64 input tile
#pragma unroll
    for (int it = 0; it < 4; ++it) {
      int lin = it * 256 + tid;
      int row = lin >> 4, k4 = (lin & 15) * 4;
      int gm = min(m0 + row, M - 1);
      *(float4*)&aT[row][k4] = *(const float4*)&src[(size_t)gm * D + kb + k4];
    }
    // stage 64x128 weight tile
#pragma unroll
    for (int it = 0; it < 8; ++it) {
      int lin = it * 256 + tid;
      int row = lin >> 5, c4 = (lin & 31) * 4;
      *(float4*)&wT[row][c4] = *(const float4*)&wsrc[(size_t)(kb + row) * D + c4];
    }
    __syncthreads();
#pragma unroll
    for (int k = 0; k < 64; k += 4) {
      float a[4][4];
#pragma unroll
      for (int i = 0; i < 4; ++i) *(float4*)&a[i][0] = *(const float4*)&aT[ty4 + i][k];
#pragma unroll
      for (int j = 0; j < 4; ++j) {
        float4 wlo = *(const float4*)&wT[k + j][tx8];
        float4 whi = *(const float4*)&wT[k + j][tx8 + 4];
#pragma unroll
        for (int i = 0; i < 4; ++i) {
          float av = a[i][j];
          acc[i][0] += av * wlo.x;
          acc[i][1] += av * wlo.y;
          acc[i][2] += av * wlo.z;
          acc[i][3] += av * wlo.w;
          acc[i][4] += av * whi.x;
          acc[i][5] += av * whi.y;
          acc[i][6] += av * whi.z;
          acc[i][7] += av * whi.w;
        }
      }
    }
    __syncthreads();
  }
  float b[8];
#pragma unroll
  for (int j = 0; j < 8; ++j) b[j] = bias ? bias[tx8 + j] : 0.f;
#pragma unroll
  for (int i = 0; i < 4; ++i) {
    int m = m0 + ty4 + i;
    if (m < M) {
      float4 lo = {acc[i][0] + b[0], acc[i][1] + b[1], acc[i][2] + b[2], acc[i][3] + b[3]};
      float4 hi = {acc[i][4] + b[4], acc[i][5] + b[5], acc[i][6] + b[6], acc[i][7] + b[7]};
      *(float4*)&out[(size_t)m * D + tx8] = lo;
      *(float4*)&out[(size_t)m * D + tx8 + 4] = hi;
    }
  }
}

// ----------------------------------------------------- per-edge MLP score
// score[e] = relu(A[s] + B[d]) . Wp2 + bp2   (bp1 folded into A)
// one wave per edge, lane l owns features [2l, 2l+1]
__global__ void edge_score_kernel(const float* __restrict__ A, const float* __restrict__ B,
                                  const int* __restrict__ s, const int* __restrict__ d,
                                  const float* __restrict__ Wp2, const float* __restrict__ bp2,
                                  float* __restrict__ out, int E) {
  int gid = blockIdx.x * blockDim.x + threadIdx.x;
  int e = gid >> 6;
  int lane = threadIdx.x & 63;
  if (e >= E) return;
  int si = s[e], di = d[e];
  float2 a = *(const float2*)(A + (size_t)si * D + lane * 2);
  float2 b = *(const float2*)(B + (size_t)di * D + lane * 2);
  float2 w = *(const float2*)(Wp2 + lane * 2);
  float x0 = a.x + b.x;
  float x1 = a.y + b.y;
  x0 = x0 > 0.f ? x0 : 0.f;
  x1 = x1 > 0.f ? x1 : 0.f;
  float p = x0 * w.x + x1 * w.y;
#pragma unroll
  for (int off = 32; off > 0; off >>= 1) p += __shfl_down(p, off);
  if (lane == 0) out[e] = p + bp2[0];
}

// ---------------------------------------------------------------- launcher
extern "C" void kernel_launch(void* const* d_in, const int* in_sizes, int n_in,
                              void* d_out, int out_size, void* d_ws, size_t ws_size,
                              hipStream_t stream) {
  const float* x = (const float*)d_in[0];
  const int* src = (const int*)d_in[1];
  const int* dst = (const int*)d_in[2];
  const int* nsrc = (const int*)d_in[3];
  const int* ndst = (const int*)d_in[4];
  const float* Ws1 = (const float*)d_in[5];
  const float* Wn1 = (const float*)d_in[6];
  const float* b1 = (const float*)d_in[7];
  const float* Ws2 = (const float*)d_in[8];
  const float* Wn2 = (const float*)d_in[9];
  const float* b2 = (const float*)d_in[10];
  const float* Ws3 = (const float*)d_in[11];
  const float* Wn3 = (const float*)d_in[12];
  const float* b3 = (const float*)d_in[13];
  const float* Wp1 = (const float*)d_in[14];
  const float* bp1 = (const float*)d_in[15];
  const float* Wp2 = (const float*)d_in[16];
  const float* bp2 = (const float*)d_in[17];
  float* out = (float*)d_out;

  char* ws = (char*)d_ws;
  size_t off = 0;
  auto alloc = [&](size_t bytes) -> void* {
    void* p = ws + off;
    off += (bytes + 255) & ~(size_t)255;
    return p;
  };
  float* buf0 = (float*)alloc(sizeof(float) * (size_t)N_NODES * D);
  float* buf1 = (float*)alloc(sizeof(float) * (size_t)N_NODES * D);
  float* buf2 = (float*)alloc(sizeof(float) * (size_t)N_NODES * D);
  int* row_start = (int*)alloc(sizeof(int) * (N_NODES + 1));
  int* deg = (int*)alloc(sizeof(int) * N_NODES * 2);  // deg + cursor contiguous
  int* cursor = deg + N_NODES;
  int* esrc = (int*)alloc(sizeof(int) * N_EDGES);
  int* partial = (int*)alloc(sizeof(int) * 128);
  (void)ws_size;

  // ---- CSR build (reused by all 3 layers)
  zero_i32<<<(2 * N_NODES + 255) / 256, 256, 0, stream>>>(deg, 2 * N_NODES);
  hist_kernel<<<(N_EDGES + 255) / 256, 256, 0, stream>>>(dst, deg, N_EDGES);
  scan_blocksum<<<SCAN_BLOCKS, 256, 0, stream>>>(deg, partial, N_NODES);
  scan_offsets<<<1, 128, 0, stream>>>(partial, row_start, SCAN_BLOCKS, N_NODES);
  scan_final<<<SCAN_BLOCKS, 256, 0, stream>>>(deg, partial, row_start, N_NODES);
  fill_kernel<<<(N_EDGES + 255) / 256, 256, 0, stream>>>(src, dst, row_start, cursor, esrc, N_EDGES);

  const int aggBlocks = (N_NODES + 3) / 4;     // 4 waves/block, 1 wave/node
  const int gemmBlocks = (N_NODES + 63) / 64;  // 64 rows/block

  // ---- layer 1: mean(x) -> buf0 ; h1 = x@Ws1 + mean@Wn1 + b1 -> buf1
  aggregate_kernel<<<aggBlocks, 256, 0, stream>>>(x, row_start, esrc, buf0, N_NODES);
  gemm_dual<true><<<gemmBlocks, 256, 0, stream>>>(x, buf0, Ws1, Wn1, b1, buf1, N_NODES);
  // ---- layer 2: h2 -> buf2
  aggregate_kernel<<<aggBlocks, 256, 0, stream>>>(buf1, row_start, esrc, buf0, N_NODES);
  gemm_dual<true><<<gemmBlocks, 256, 0, stream>>>(buf1, buf0, Ws2, Wn2, b2, buf2, N_NODES);
  // ---- layer 3: h3 -> buf1
  aggregate_kernel<<<aggBlocks, 256, 0, stream>>>(buf2, row_start, esrc, buf0, N_NODES);
  gemm_dual<true><<<gemmBlocks, 256, 0, stream>>>(buf2, buf0, Ws3, Wn3, b3, buf1, N_NODES);
  // ---- predictor precompute: A = h3@Wp1_top + bp1 -> buf0 ; B = h3@Wp1_bot -> buf2
  gemm_dual<false><<<gemmBlocks, 256, 0, stream>>>(buf1, nullptr, Wp1, nullptr, bp1, buf0, N_NODES);
  gemm_dual<false><<<gemmBlocks, 256, 0, stream>>>(buf1, nullptr, Wp1 + D * D, nullptr, nullptr, buf2, N_NODES);
  // ---- edge scores: pos then neg, concatenated in d_out
  edge_score_kernel<<<N_EDGES / 4, 256, 0, stream>>>(buf0, buf2, src, dst, Wp2, bp2, out, N_EDGES);
  edge_score_kernel<<<N_EDGES / 4, 256, 0, stream>>>(buf0, buf2, nsrc, ndst, Wp2, bp2, out + N_EDGES, N_EDGES);
}

// Round 3
// 939.174 us; speedup vs baseline: 1.3068x; 1.1461x over previous
//
#include <hip/hip_runtime.h>

#define N_NODES 100000
#define N_EDGES 640000
#define D 128
#define SCAN_TILE 1024
#define SCAN_BLOCKS ((N_NODES + SCAN_TILE - 1) / SCAN_TILE)  // 98

typedef __attribute__((ext_vector_type(8))) short bf16x8;   // 8 bf16 = 4 VGPRs
typedef __attribute__((ext_vector_type(4))) float f32x4;

__device__ __forceinline__ unsigned short f32_to_bf16(float f) {
  union { float f; unsigned int u; } v; v.f = f;
  unsigned int u = v.u;
  unsigned int r = (u + 0x7fffu + ((u >> 16) & 1u)) >> 16;  // RNE
  return (unsigned short)r;
}

// ---------------------------------------------------------------- utilities
__global__ void zero_i32(int* __restrict__ p, int n) {
  int i = blockIdx.x * blockDim.x + threadIdx.x;
  if (i < n) p[i] = 0;
}

// fp32 -> bf16, 4 elems/thread
__global__ void f32_to_bf16_vec(const float* __restrict__ in, unsigned short* __restrict__ out, int n4) {
  int i = blockIdx.x * blockDim.x + threadIdx.x;
  if (i < n4) {
    float4 v = ((const float4*)in)[i];
    ushort4 o;
    o.x = f32_to_bf16(v.x); o.y = f32_to_bf16(v.y);
    o.z = f32_to_bf16(v.z); o.w = f32_to_bf16(v.w);
    ((ushort4*)out)[i] = o;
  }
}

// 8 weight matrices [128x128] fp32 row-major [k][n] -> bf16 transposed Wt[n][k]
__global__ void transpose_w(const float* __restrict__ W0, const float* __restrict__ W1,
                            const float* __restrict__ W2, const float* __restrict__ W3,
                            const float* __restrict__ W4, const float* __restrict__ W5,
                            const float* __restrict__ W6, const float* __restrict__ W7,
                            unsigned short* __restrict__ wt) {
  int id = blockIdx.x * 256 + threadIdx.x;  // 512 blocks x 256 = 131072
  int mat = id >> 14;
  int rem = id & 16383;
  int n = rem >> 7, k = rem & 127;
  const float* Wm = mat < 4 ? (mat < 2 ? (mat == 0 ? W0 : W1) : (mat == 2 ? W2 : W3))
                            : (mat < 6 ? (mat == 4 ? W4 : W5) : (mat == 6 ? W6 : W7));
  wt[id] = f32_to_bf16(Wm[k * D + n]);
}

// ------------------------------------------------------------- CSR building
__global__ void hist_kernel(const int* __restrict__ dst, int* __restrict__ deg, int E) {
  int i = blockIdx.x * blockDim.x + threadIdx.x;
  if (i < E) atomicAdd(&deg[dst[i]], 1);
}

__global__ void scan_blocksum(const int* __restrict__ deg, int* __restrict__ partial, int n) {
  __shared__ int lds[256];
  const int tid = threadIdx.x;
  const int base = blockIdx.x * SCAN_TILE + tid * 4;
  int s = 0;
#pragma unroll
  for (int j = 0; j < 4; ++j) {
    int i = base + j;
    if (i < n) s += deg[i];
  }
  lds[tid] = s;
  __syncthreads();
  for (int off = 128; off > 0; off >>= 1) {
    if (tid < off) lds[tid] += lds[tid + off];
    __syncthreads();
  }
  if (tid == 0) partial[blockIdx.x] = lds[0];
}

__global__ void scan_offsets(int* __restrict__ partial, int* __restrict__ row_start, int nb, int n) {
  __shared__ int lds[128];
  const int tid = threadIdx.x;
  int v = (tid < nb) ? partial[tid] : 0;
  lds[tid] = v;
  __syncthreads();
  for (int off = 1; off < 128; off <<= 1) {
    int t = (tid >= off) ? lds[tid - off] : 0;
    __syncthreads();
    lds[tid] += t;
    __syncthreads();
  }
  if (tid < nb) partial[tid] = (tid == 0) ? 0 : lds[tid - 1];
  if (tid == 0) row_start[n] = lds[nb - 1];
}

__global__ void scan_final(const int* __restrict__ deg, const int* __restrict__ partial,
                           int* __restrict__ row_start, int n) {
  __shared__ int lds[256];
  const int tid = threadIdx.x;
  const int base = blockIdx.x * SCAN_TILE + tid * 4;
  int d[4];
  int s = 0;
#pragma unroll
  for (int j = 0; j < 4; ++j) {
    int i = base + j;
    d[j] = (i < n) ? deg[i] : 0;
    s += d[j];
  }
  lds[tid] = s;
  __syncthreads();
  for (int off = 1; off < 256; off <<= 1) {
    int t = (tid >= off) ? lds[tid - off] : 0;
    __syncthreads();
    lds[tid] += t;
    __syncthreads();
  }
  int pre = partial[blockIdx.x] + lds[tid] - s;
#pragma unroll
  for (int j = 0; j < 4; ++j) {
    int i = base + j;
    if (i < n) {
      row_start[i] = pre;
      pre += d[j];
    }
  }
}

__global__ void fill_kernel(const int* __restrict__ src, const int* __restrict__ dst,
                            const int* __restrict__ row_start, int* __restrict__ cursor,
                            int* __restrict__ esrc, int E) {
  int i = blockIdx.x * blockDim.x + threadIdx.x;
  if (i < E) {
    int d = dst[i];
    int pos = atomicAdd(&cursor[d], 1);
    esrc[row_start[d] + pos] = src[i];
  }
}

// ----------------------------------------------------- mean aggregation (bf16 I/O)
// one wave per node; lane l owns features [2l, 2l+1]
__global__ void aggregate_bf16(const unsigned short* __restrict__ h, const int* __restrict__ row_start,
                               const int* __restrict__ esrc, unsigned short* __restrict__ mean, int n) {
  int gid = blockIdx.x * blockDim.x + threadIdx.x;
  int node = gid >> 6;
  int lane = threadIdx.x & 63;
  if (node >= n) return;
  int s0 = row_start[node], s1 = row_start[node + 1];
  float ax = 0.f, ay = 0.f;
  for (int e = s0; e < s1; ++e) {
    int s = esrc[e];
    unsigned int w = *(const unsigned int*)(h + (size_t)s * D + lane * 2);
    ax += __uint_as_float(w << 16);
    ay += __uint_as_float(w & 0xffff0000u);
  }
  float inv = 1.0f / (float)max(s1 - s0, 1);
  ax *= inv; ay *= inv;
  unsigned int lo = f32_to_bf16(ax), hi = f32_to_bf16(ay);
  *(unsigned int*)(mean + (size_t)node * D + lane * 2) = lo | (hi << 16);
}

// ----------------------------------------------------- MFMA bf16 GEMM
// out[M,128] = in0 @ W0 (+ in1 @ W1) + bias.  Wt transposed [n][k] bf16.
// 256 thr = 4 waves; wave computes 16 rows x 128 cols, K = NCHUNK*128.
// A-frag: m=lane&15, k=q*8+j (16B contiguous).  B-frag: n=lane&15, k=q*8+j.
// C/D: col=lane&15, row=q*4+reg (verified layout).
template <int NCHUNK, bool FP32OUT>
__global__ __launch_bounds__(256) void gemm_mfma(
    const unsigned short* __restrict__ in0, const unsigned short* __restrict__ in1,
    const unsigned short* __restrict__ Wt0, const unsigned short* __restrict__ Wt1,
    const float* __restrict__ bias, void* __restrict__ out, int M) {
  const int lane = threadIdx.x & 63;
  const int wave = threadIdx.x >> 6;
  const int m0 = blockIdx.x * 64 + wave * 16;
  const int row = lane & 15;
  const int q = lane >> 4;
  const int mload = min(m0 + row, M - 1);

  bf16x8 afrag[NCHUNK * 4];
#pragma unroll
  for (int s = 0; s < NCHUNK * 4; ++s) {
    const unsigned short* src = (NCHUNK == 2 && s >= 4) ? in1 : in0;
    afrag[s] = *reinterpret_cast<const bf16x8*>(src + (size_t)mload * D + (s & 3) * 32 + q * 8);
  }
  f32x4 acc[8];
#pragma unroll
  for (int t = 0; t < 8; ++t) acc[t] = (f32x4){0.f, 0.f, 0.f, 0.f};

#pragma unroll
  for (int t = 0; t < 8; ++t) {
    const int n = t * 16 + row;
#pragma unroll
    for (int s = 0; s < NCHUNK * 4; ++s) {
      const unsigned short* wb = (NCHUNK == 2 && s >= 4) ? Wt1 : Wt0;
      bf16x8 b = *reinterpret_cast<const bf16x8*>(wb + (size_t)n * D + (s & 3) * 32 + q * 8);
      acc[t] = __builtin_amdgcn_mfma_f32_16x16x32_bf16(afrag[s], b, acc[t], 0, 0, 0);
    }
  }

#pragma unroll
  for (int t = 0; t < 8; ++t) {
    const int col = t * 16 + row;
    const float bv = bias ? bias[col] : 0.f;
#pragma unroll
    for (int r = 0; r < 4; ++r) {
      int m = m0 + q * 4 + r;
      if (m < M) {
        float v = acc[t][r] + bv;
        if (FP32OUT)
          ((float*)out)[(size_t)m * D + col] = v;
        else
          ((unsigned short*)out)[(size_t)m * D + col] = f32_to_bf16(v);
      }
    }
  }
}

// ----------------------------------------------------- per-edge MLP score (fp32 A/B)
__global__ void edge_score_kernel(const float* __restrict__ A, const float* __restrict__ B,
                                  const int* __restrict__ s, const int* __restrict__ d,
                                  const float* __restrict__ Wp2, const float* __restrict__ bp2,
                                  float* __restrict__ out, int E) {
  int gid = blockIdx.x * blockDim.x + threadIdx.x;
  int e = gid >> 6;
  int lane = threadIdx.x & 63;
  if (e >= E) return;
  int si = s[e], di = d[e];
  float2 a = *(const float2*)(A + (size_t)si * D + lane * 2);
  float2 b = *(const float2*)(B + (size_t)di * D + lane * 2);
  float2 w = *(const float2*)(Wp2 + lane * 2);
  float x0 = a.x + b.x;
  float x1 = a.y + b.y;
  x0 = x0 > 0.f ? x0 : 0.f;
  x1 = x1 > 0.f ? x1 : 0.f;
  float p = x0 * w.x + x1 * w.y;
#pragma unroll
  for (int off = 32; off > 0; off >>= 1) p += __shfl_down(p, off);
  if (lane == 0) out[e] = p + bp2[0];
}

// ---------------------------------------------------------------- launcher
extern "C" void kernel_launch(void* const* d_in, const int* in_sizes, int n_in,
                              void* d_out, int out_size, void* d_ws, size_t ws_size,
                              hipStream_t stream) {
  const float* x = (const float*)d_in[0];
  const int* src = (const int*)d_in[1];
  const int* dst = (const int*)d_in[2];
  const int* nsrc = (const int*)d_in[3];
  const int* ndst = (const int*)d_in[4];
  const float* Ws1 = (const float*)d_in[5];
  const float* Wn1 = (const float*)d_in[6];
  const float* b1 = (const float*)d_in[7];
  const float* Ws2 = (const float*)d_in[8];
  const float* Wn2 = (const float*)d_in[9];
  const float* b2 = (const float*)d_in[10];
  const float* Ws3 = (const float*)d_in[11];
  const float* Wn3 = (const float*)d_in[12];
  const float* b3 = (const float*)d_in[13];
  const float* Wp1 = (const float*)d_in[14];
  const float* bp1 = (const float*)d_in[15];
  const float* Wp2 = (const float*)d_in[16];
  const float* bp2 = (const float*)d_in[17];
  float* out = (float*)d_out;

  char* ws = (char*)d_ws;
  size_t off = 0;
  auto alloc = [&](size_t bytes) -> void* {
    void* p = ws + off;
    off += (bytes + 255) & ~(size_t)255;
    return p;
  };
  const size_t NODE_F32 = sizeof(float) * (size_t)N_NODES * D;  // 51.2 MB
  // region0: bf16 xb | bf16 mean  (later reused as fp32 B)
  char* region0 = (char*)alloc(NODE_F32);
  // region1: bf16 h_A | bf16 h_B
  char* region1 = (char*)alloc(NODE_F32);
  // region2: fp32 A
  float* Af = (float*)alloc(NODE_F32);
  int* row_start = (int*)alloc(sizeof(int) * (N_NODES + 1));
  int* deg = (int*)alloc(sizeof(int) * N_NODES * 2);
  int* cursor = deg + N_NODES;
  int* esrc = (int*)alloc(sizeof(int) * N_EDGES);
  int* partial = (int*)alloc(sizeof(int) * 128);
  unsigned short* wt = (unsigned short*)alloc(sizeof(unsigned short) * 8 * D * D);
  (void)ws_size;

  unsigned short* xb = (unsigned short*)region0;
  unsigned short* meanb = xb + (size_t)N_NODES * D;
  unsigned short* hA = (unsigned short*)region1;
  unsigned short* hB = hA + (size_t)N_NODES * D;
  float* Bf = (float*)region0;  // aliases xb+meanb (dead by predictor stage)

  // ---- conversions
  f32_to_bf16_vec<<<(N_NODES * D / 4 + 255) / 256, 256, 0, stream>>>(x, xb, N_NODES * D / 4);
  transpose_w<<<512, 256, 0, stream>>>(Ws1, Wn1, Ws2, Wn2, Ws3, Wn3, Wp1, Wp1 + D * D, wt);

  // ---- CSR build (reused by all 3 layers)
  zero_i32<<<(2 * N_NODES + 255) / 256, 256, 0, stream>>>(deg, 2 * N_NODES);
  hist_kernel<<<(N_EDGES + 255) / 256, 256, 0, stream>>>(dst, deg, N_EDGES);
  scan_blocksum<<<SCAN_BLOCKS, 256, 0, stream>>>(deg, partial, N_NODES);
  scan_offsets<<<1, 128, 0, stream>>>(partial, row_start, SCAN_BLOCKS, N_NODES);
  scan_final<<<SCAN_BLOCKS, 256, 0, stream>>>(deg, partial, row_start, N_NODES);
  fill_kernel<<<(N_EDGES + 255) / 256, 256, 0, stream>>>(src, dst, row_start, cursor, esrc, N_EDGES);

  const int aggBlocks = (N_NODES + 3) / 4;
  const int gemmBlocks = (N_NODES + 63) / 64;

  // ---- layer 1
  aggregate_bf16<<<aggBlocks, 256, 0, stream>>>(xb, row_start, esrc, meanb, N_NODES);
  gemm_mfma<2, false><<<gemmBlocks, 256, 0, stream>>>(xb, meanb, wt, wt + 16384, b1, hA, N_NODES);
  // ---- layer 2
  aggregate_bf16<<<aggBlocks, 256, 0, stream>>>(hA, row_start, esrc, meanb, N_NODES);
  gemm_mfma<2, false><<<gemmBlocks, 256, 0, stream>>>(hA, meanb, wt + 2 * 16384, wt + 3 * 16384, b2, hB, N_NODES);
  // ---- layer 3
  aggregate_bf16<<<aggBlocks, 256, 0, stream>>>(hB, row_start, esrc, meanb, N_NODES);
  gemm_mfma<2, false><<<gemmBlocks, 256, 0, stream>>>(hB, meanb, wt + 4 * 16384, wt + 5 * 16384, b3, hA, N_NODES);
  // ---- predictor precompute: A = h3@Wp1_top + bp1 (fp32), B = h3@Wp1_bot (fp32)
  gemm_mfma<1, true><<<gemmBlocks, 256, 0, stream>>>(hA, nullptr, wt + 6 * 16384, nullptr, bp1, Af, N_NODES);
  gemm_mfma<1, true><<<gemmBlocks, 256, 0, stream>>>(hA, nullptr, wt + 7 * 16384, nullptr, nullptr, Bf, N_NODES);
  // ---- edge scores
  edge_score_kernel<<<N_EDGES / 4, 256, 0, stream>>>(Af, Bf, src, dst, Wp2, bp2, out, N_EDGES);
  edge_score_kernel<<<N_EDGES / 4, 256, 0, stream>>>(Af, Bf, nsrc, ndst, Wp2, bp2, out + N_EDGES, N_EDGES);
}

// Round 4
// 906.856 us; speedup vs baseline: 1.3534x; 1.0356x over previous
//
#include <hip/hip_runtime.h>

#define N_NODES 100000
#define N_EDGES 640000
#define D 128
#define SCAN_TILE 1024
#define SCAN_BLOCKS ((N_NODES + SCAN_TILE - 1) / SCAN_TILE)  // 98

typedef __attribute__((ext_vector_type(8))) short bf16x8;   // 8 bf16 = 4 VGPRs
typedef __attribute__((ext_vector_type(4))) float f32x4;

__device__ __forceinline__ unsigned short f32_to_bf16(float f) {
  union { float f; unsigned int u; } v; v.f = f;
  unsigned int u = v.u;
  unsigned int r = (u + 0x7fffu + ((u >> 16) & 1u)) >> 16;  // RNE
  return (unsigned short)r;
}

// ---------------------------------------------------------------- utilities
__global__ void zero_i32(int* __restrict__ p, int n) {
  int i = blockIdx.x * blockDim.x + threadIdx.x;
  if (i < n) p[i] = 0;
}

// fp32 -> bf16, 4 elems/thread
__global__ void f32_to_bf16_vec(const float* __restrict__ in, unsigned short* __restrict__ out, int n4) {
  int i = blockIdx.x * blockDim.x + threadIdx.x;
  if (i < n4) {
    float4 v = ((const float4*)in)[i];
    ushort4 o;
    o.x = f32_to_bf16(v.x); o.y = f32_to_bf16(v.y);
    o.z = f32_to_bf16(v.z); o.w = f32_to_bf16(v.w);
    ((ushort4*)out)[i] = o;
  }
}

// 8 weight matrices [128x128] fp32 row-major [k][n] -> bf16 transposed Wt[n][k]
__global__ void transpose_w(const float* __restrict__ W0, const float* __restrict__ W1,
                            const float* __restrict__ W2, const float* __restrict__ W3,
                            const float* __restrict__ W4, const float* __restrict__ W5,
                            const float* __restrict__ W6, const float* __restrict__ W7,
                            unsigned short* __restrict__ wt) {
  int id = blockIdx.x * 256 + threadIdx.x;  // 512 blocks x 256 = 131072
  int mat = id >> 14;
  int rem = id & 16383;
  int n = rem >> 7, k = rem & 127;
  const float* Wm = mat < 4 ? (mat < 2 ? (mat == 0 ? W0 : W1) : (mat == 2 ? W2 : W3))
                            : (mat < 6 ? (mat == 4 ? W4 : W5) : (mat == 6 ? W6 : W7));
  wt[id] = f32_to_bf16(Wm[k * D + n]);
}

// ------------------------------------------------------------- CSR building
__global__ void hist_kernel(const int* __restrict__ dst, int* __restrict__ deg, int E) {
  int i = blockIdx.x * blockDim.x + threadIdx.x;
  if (i < E) atomicAdd(&deg[dst[i]], 1);
}

__global__ void scan_blocksum(const int* __restrict__ deg, int* __restrict__ partial, int n) {
  __shared__ int lds[256];
  const int tid = threadIdx.x;
  const int base = blockIdx.x * SCAN_TILE + tid * 4;
  int s = 0;
#pragma unroll
  for (int j = 0; j < 4; ++j) {
    int i = base + j;
    if (i < n) s += deg[i];
  }
  lds[tid] = s;
  __syncthreads();
  for (int off = 128; off > 0; off >>= 1) {
    if (tid < off) lds[tid] += lds[tid + off];
    __syncthreads();
  }
  if (tid == 0) partial[blockIdx.x] = lds[0];
}

__global__ void scan_offsets(int* __restrict__ partial, int* __restrict__ row_start, int nb, int n) {
  __shared__ int lds[128];
  const int tid = threadIdx.x;
  int v = (tid < nb) ? partial[tid] : 0;
  lds[tid] = v;
  __syncthreads();
  for (int off = 1; off < 128; off <<= 1) {
    int t = (tid >= off) ? lds[tid - off] : 0;
    __syncthreads();
    lds[tid] += t;
    __syncthreads();
  }
  if (tid < nb) partial[tid] = (tid == 0) ? 0 : lds[tid - 1];
  if (tid == 0) row_start[n] = lds[nb - 1];
}

__global__ void scan_final(const int* __restrict__ deg, const int* __restrict__ partial,
                           int* __restrict__ row_start, int n) {
  __shared__ int lds[256];
  const int tid = threadIdx.x;
  const int base = blockIdx.x * SCAN_TILE + tid * 4;
  int d[4];
  int s = 0;
#pragma unroll
  for (int j = 0; j < 4; ++j) {
    int i = base + j;
    d[j] = (i < n) ? deg[i] : 0;
    s += d[j];
  }
  lds[tid] = s;
  __syncthreads();
  for (int off = 1; off < 256; off <<= 1) {
    int t = (tid >= off) ? lds[tid - off] : 0;
    __syncthreads();
    lds[tid] += t;
    __syncthreads();
  }
  int pre = partial[blockIdx.x] + lds[tid] - s;
#pragma unroll
  for (int j = 0; j < 4; ++j) {
    int i = base + j;
    if (i < n) {
      row_start[i] = pre;
      pre += d[j];
    }
  }
}

__global__ void fill_kernel(const int* __restrict__ src, const int* __restrict__ dst,
                            const int* __restrict__ row_start, int* __restrict__ cursor,
                            int* __restrict__ esrc, int E) {
  int i = blockIdx.x * blockDim.x + threadIdx.x;
  if (i < E) {
    int d = dst[i];
    int pos = atomicAdd(&cursor[d], 1);
    esrc[row_start[d] + pos] = src[i];
  }
}

// ----------------------------------------------------- mean aggregation (bf16 I/O)
// one wave per node; lane l owns features [2l, 2l+1]
__global__ void aggregate_bf16(const unsigned short* __restrict__ h, const int* __restrict__ row_start,
                               const int* __restrict__ esrc, unsigned short* __restrict__ mean, int n) {
  int gid = blockIdx.x * blockDim.x + threadIdx.x;
  int node = gid >> 6;
  int lane = threadIdx.x & 63;
  if (node >= n) return;
  int s0 = row_start[node], s1 = row_start[node + 1];
  float ax = 0.f, ay = 0.f;
  for (int e = s0; e < s1; ++e) {
    int s = esrc[e];
    unsigned int w = *(const unsigned int*)(h + (size_t)s * D + lane * 2);
    ax += __uint_as_float(w << 16);
    ay += __uint_as_float(w & 0xffff0000u);
  }
  float inv = 1.0f / (float)max(s1 - s0, 1);
  ax *= inv; ay *= inv;
  unsigned int lo = f32_to_bf16(ax), hi = f32_to_bf16(ay);
  *(unsigned int*)(mean + (size_t)node * D + lane * 2) = lo | (hi << 16);
}

// ----------------------------------------------------- MFMA bf16 GEMM
// out[M,128] = in0 @ W0 (+ in1 @ W1) + bias.  Wt transposed [n][k] bf16.
// 256 thr = 4 waves; wave computes 16 rows x 128 cols, K = NCHUNK*128.
template <int NCHUNK, bool FP32OUT>
__global__ __launch_bounds__(256) void gemm_mfma(
    const unsigned short* __restrict__ in0, const unsigned short* __restrict__ in1,
    const unsigned short* __restrict__ Wt0, const unsigned short* __restrict__ Wt1,
    const float* __restrict__ bias, void* __restrict__ out, int M) {
  const int lane = threadIdx.x & 63;
  const int wave = threadIdx.x >> 6;
  const int m0 = blockIdx.x * 64 + wave * 16;
  const int row = lane & 15;
  const int q = lane >> 4;
  const int mload = min(m0 + row, M - 1);

  bf16x8 afrag[NCHUNK * 4];
#pragma unroll
  for (int s = 0; s < NCHUNK * 4; ++s) {
    const unsigned short* src = (NCHUNK == 2 && s >= 4) ? in1 : in0;
    afrag[s] = *reinterpret_cast<const bf16x8*>(src + (size_t)mload * D + (s & 3) * 32 + q * 8);
  }
  f32x4 acc[8];
#pragma unroll
  for (int t = 0; t < 8; ++t) acc[t] = (f32x4){0.f, 0.f, 0.f, 0.f};

#pragma unroll
  for (int t = 0; t < 8; ++t) {
    const int n = t * 16 + row;
#pragma unroll
    for (int s = 0; s < NCHUNK * 4; ++s) {
      const unsigned short* wb = (NCHUNK == 2 && s >= 4) ? Wt1 : Wt0;
      bf16x8 b = *reinterpret_cast<const bf16x8*>(wb + (size_t)n * D + (s & 3) * 32 + q * 8);
      acc[t] = __builtin_amdgcn_mfma_f32_16x16x32_bf16(afrag[s], b, acc[t], 0, 0, 0);
    }
  }

#pragma unroll
  for (int t = 0; t < 8; ++t) {
    const int col = t * 16 + row;
    const float bv = bias ? bias[col] : 0.f;
#pragma unroll
    for (int r = 0; r < 4; ++r) {
      int m = m0 + q * 4 + r;
      if (m < M) {
        float v = acc[t][r] + bv;
        if (FP32OUT)
          ((float*)out)[(size_t)m * D + col] = v;
        else
          ((unsigned short*)out)[(size_t)m * D + col] = f32_to_bf16(v);
      }
    }
  }
}

// ----------------------------------------------------- per-edge MLP score (bf16 A/B)
// score[e] = relu(A[s] + B[d]) . Wp2 + bp2   (bp1 folded into A)
// one wave per edge; lane l owns features [2l, 2l+1] (4 B/lane per row)
__global__ void edge_score_bf16(const unsigned short* __restrict__ A, const unsigned short* __restrict__ B,
                                const int* __restrict__ s, const int* __restrict__ d,
                                const float* __restrict__ Wp2, const float* __restrict__ bp2,
                                float* __restrict__ out, int E) {
  int gid = blockIdx.x * blockDim.x + threadIdx.x;
  int e = gid >> 6;
  int lane = threadIdx.x & 63;
  if (e >= E) return;
  int si = s[e], di = d[e];
  unsigned int ua = *(const unsigned int*)(A + (size_t)si * D + lane * 2);
  unsigned int ub = *(const unsigned int*)(B + (size_t)di * D + lane * 2);
  float a0 = __uint_as_float(ua << 16);
  float a1 = __uint_as_float(ua & 0xffff0000u);
  float b0 = __uint_as_float(ub << 16);
  float b1 = __uint_as_float(ub & 0xffff0000u);
  float2 w = *(const float2*)(Wp2 + lane * 2);
  float x0 = a0 + b0;
  float x1 = a1 + b1;
  x0 = x0 > 0.f ? x0 : 0.f;
  x1 = x1 > 0.f ? x1 : 0.f;
  float p = x0 * w.x + x1 * w.y;
#pragma unroll
  for (int off = 32; off > 0; off >>= 1) p += __shfl_down(p, off);
  if (lane == 0) out[e] = p + bp2[0];
}

// ---------------------------------------------------------------- launcher
extern "C" void kernel_launch(void* const* d_in, const int* in_sizes, int n_in,
                              void* d_out, int out_size, void* d_ws, size_t ws_size,
                              hipStream_t stream) {
  const float* x = (const float*)d_in[0];
  const int* src = (const int*)d_in[1];
  const int* dst = (const int*)d_in[2];
  const int* nsrc = (const int*)d_in[3];
  const int* ndst = (const int*)d_in[4];
  const float* Ws1 = (const float*)d_in[5];
  const float* Wn1 = (const float*)d_in[6];
  const float* b1 = (const float*)d_in[7];
  const float* Ws2 = (const float*)d_in[8];
  const float* Wn2 = (const float*)d_in[9];
  const float* b2 = (const float*)d_in[10];
  const float* Ws3 = (const float*)d_in[11];
  const float* Wn3 = (const float*)d_in[12];
  const float* b3 = (const float*)d_in[13];
  const float* Wp1 = (const float*)d_in[14];
  const float* bp1 = (const float*)d_in[15];
  const float* Wp2 = (const float*)d_in[16];
  const float* bp2 = (const float*)d_in[17];
  float* out = (float*)d_out;

  char* ws = (char*)d_ws;
  size_t off = 0;
  auto alloc = [&](size_t bytes) -> void* {
    void* p = ws + off;
    off += (bytes + 255) & ~(size_t)255;
    return p;
  };
  const size_t NODE_F32 = sizeof(float) * (size_t)N_NODES * D;  // 51.2 MB
  // region0: bf16 xb | bf16 mean
  char* region0 = (char*)alloc(NODE_F32);
  // region1: bf16 h_A | bf16 h_B
  char* region1 = (char*)alloc(NODE_F32);
  // region2: bf16 A | bf16 B (predictor precompute)
  char* region2 = (char*)alloc(NODE_F32);
  int* row_start = (int*)alloc(sizeof(int) * (N_NODES + 1));
  int* deg = (int*)alloc(sizeof(int) * N_NODES * 2);
  int* cursor = deg + N_NODES;
  int* esrc = (int*)alloc(sizeof(int) * N_EDGES);
  int* partial = (int*)alloc(sizeof(int) * 128);
  unsigned short* wt = (unsigned short*)alloc(sizeof(unsigned short) * 8 * D * D);
  (void)ws_size;

  unsigned short* xb = (unsigned short*)region0;
  unsigned short* meanb = xb + (size_t)N_NODES * D;
  unsigned short* hA = (unsigned short*)region1;
  unsigned short* hB = hA + (size_t)N_NODES * D;
  unsigned short* Ab = (unsigned short*)region2;
  unsigned short* Bb = Ab + (size_t)N_NODES * D;

  // ---- conversions
  f32_to_bf16_vec<<<(N_NODES * D / 4 + 255) / 256, 256, 0, stream>>>(x, xb, N_NODES * D / 4);
  transpose_w<<<512, 256, 0, stream>>>(Ws1, Wn1, Ws2, Wn2, Ws3, Wn3, Wp1, Wp1 + D * D, wt);

  // ---- CSR build (reused by all 3 layers)
  zero_i32<<<(2 * N_NODES + 255) / 256, 256, 0, stream>>>(deg, 2 * N_NODES);
  hist_kernel<<<(N_EDGES + 255) / 256, 256, 0, stream>>>(dst, deg, N_EDGES);
  scan_blocksum<<<SCAN_BLOCKS, 256, 0, stream>>>(deg, partial, N_NODES);
  scan_offsets<<<1, 128, 0, stream>>>(partial, row_start, SCAN_BLOCKS, N_NODES);
  scan_final<<<SCAN_BLOCKS, 256, 0, stream>>>(deg, partial, row_start, N_NODES);
  fill_kernel<<<(N_EDGES + 255) / 256, 256, 0, stream>>>(src, dst, row_start, cursor, esrc, N_EDGES);

  const int aggBlocks = (N_NODES + 3) / 4;
  const int gemmBlocks = (N_NODES + 63) / 64;

  // ---- layer 1
  aggregate_bf16<<<aggBlocks, 256, 0, stream>>>(xb, row_start, esrc, meanb, N_NODES);
  gemm_mfma<2, false><<<gemmBlocks, 256, 0, stream>>>(xb, meanb, wt, wt + 16384, b1, hA, N_NODES);
  // ---- layer 2
  aggregate_bf16<<<aggBlocks, 256, 0, stream>>>(hA, row_start, esrc, meanb, N_NODES);
  gemm_mfma<2, false><<<gemmBlocks, 256, 0, stream>>>(hA, meanb, wt + 2 * 16384, wt + 3 * 16384, b2, hB, N_NODES);
  // ---- layer 3
  aggregate_bf16<<<aggBlocks, 256, 0, stream>>>(hB, row_start, esrc, meanb, N_NODES);
  gemm_mfma<2, false><<<gemmBlocks, 256, 0, stream>>>(hB, meanb, wt + 4 * 16384, wt + 5 * 16384, b3, hA, N_NODES);
  // ---- predictor precompute: A = h3@Wp1_top + bp1 (bf16), B = h3@Wp1_bot (bf16)
  gemm_mfma<1, false><<<gemmBlocks, 256, 0, stream>>>(hA, nullptr, wt + 6 * 16384, nullptr, bp1, Ab, N_NODES);
  gemm_mfma<1, false><<<gemmBlocks, 256, 0, stream>>>(hA, nullptr, wt + 7 * 16384, nullptr, nullptr, Bb, N_NODES);
  // ---- edge scores
  edge_score_bf16<<<N_EDGES / 4, 256, 0, stream>>>(Ab, Bb, src, dst, Wp2, bp2, out, N_EDGES);
  edge_score_bf16<<<N_EDGES / 4, 256, 0, stream>>>(Ab, Bb, nsrc, ndst, Wp2, bp2, out + N_EDGES, N_EDGES);
}

// Round 5
// 667.341 us; speedup vs baseline: 1.8392x; 1.3589x over previous
//
#include <hip/hip_runtime.h>

#define N_NODES 100000
#define N_EDGES 640000
#define D 128
#define SCAN_TILE 1024
#define SCAN_BLOCKS ((N_NODES + SCAN_TILE - 1) / SCAN_TILE)  // 98

typedef __attribute__((ext_vector_type(8))) short bf16x8;   // 8 bf16 = 4 VGPRs
typedef __attribute__((ext_vector_type(4))) float f32x4;

__device__ __forceinline__ unsigned short f32_to_bf16(float f) {
  union { float f; unsigned int u; } v; v.f = f;
  unsigned int u = v.u;
  unsigned int r = (u + 0x7fffu + ((u >> 16) & 1u)) >> 16;  // RNE
  return (unsigned short)r;
}
__device__ __forceinline__ float bf16_lo(unsigned int u) { return __uint_as_float(u << 16); }
__device__ __forceinline__ float bf16_hi(unsigned int u) { return __uint_as_float(u & 0xffff0000u); }

// ---------------------------------------------------------------- utilities
__global__ void zero_i32(int* __restrict__ p, int n) {
  int i = blockIdx.x * blockDim.x + threadIdx.x;
  if (i < n) p[i] = 0;
}

// fp32 -> bf16, 4 elems/thread
__global__ void f32_to_bf16_vec(const float* __restrict__ in, unsigned short* __restrict__ out, int n4) {
  int i = blockIdx.x * blockDim.x + threadIdx.x;
  if (i < n4) {
    float4 v = ((const float4*)in)[i];
    ushort4 o;
    o.x = f32_to_bf16(v.x); o.y = f32_to_bf16(v.y);
    o.z = f32_to_bf16(v.z); o.w = f32_to_bf16(v.w);
    ((ushort4*)out)[i] = o;
  }
}

// 8 weight matrices [128x128] fp32 row-major [k][n] -> bf16 transposed Wt[n][k]
__global__ void transpose_w(const float* __restrict__ W0, const float* __restrict__ W1,
                            const float* __restrict__ W2, const float* __restrict__ W3,
                            const float* __restrict__ W4, const float* __restrict__ W5,
                            const float* __restrict__ W6, const float* __restrict__ W7,
                            unsigned short* __restrict__ wt) {
  int id = blockIdx.x * 256 + threadIdx.x;  // 512 blocks x 256 = 131072
  int mat = id >> 14;
  int rem = id & 16383;
  int n = rem >> 7, k = rem & 127;
  const float* Wm = mat < 4 ? (mat < 2 ? (mat == 0 ? W0 : W1) : (mat == 2 ? W2 : W3))
                            : (mat < 6 ? (mat == 4 ? W4 : W5) : (mat == 6 ? W6 : W7));
  wt[id] = f32_to_bf16(Wm[k * D + n]);
}

// ------------------------------------------------------------- CSR building
__global__ void hist_kernel(const int* __restrict__ dst, int* __restrict__ deg, int E) {
  int i = blockIdx.x * blockDim.x + threadIdx.x;
  if (i < E) atomicAdd(&deg[dst[i]], 1);
}

__global__ void scan_blocksum(const int* __restrict__ deg, int* __restrict__ partial, int n) {
  __shared__ int lds[256];
  const int tid = threadIdx.x;
  const int base = blockIdx.x * SCAN_TILE + tid * 4;
  int s = 0;
#pragma unroll
  for (int j = 0; j < 4; ++j) {
    int i = base + j;
    if (i < n) s += deg[i];
  }
  lds[tid] = s;
  __syncthreads();
  for (int off = 128; off > 0; off >>= 1) {
    if (tid < off) lds[tid] += lds[tid + off];
    __syncthreads();
  }
  if (tid == 0) partial[blockIdx.x] = lds[0];
}

__global__ void scan_offsets(int* __restrict__ partial, int* __restrict__ row_start, int nb, int n) {
  __shared__ int lds[128];
  const int tid = threadIdx.x;
  int v = (tid < nb) ? partial[tid] : 0;
  lds[tid] = v;
  __syncthreads();
  for (int off = 1; off < 128; off <<= 1) {
    int t = (tid >= off) ? lds[tid - off] : 0;
    __syncthreads();
    lds[tid] += t;
    __syncthreads();
  }
  if (tid < nb) partial[tid] = (tid == 0) ? 0 : lds[tid - 1];
  if (tid == 0) row_start[n] = lds[nb - 1];
}

__global__ void scan_final(const int* __restrict__ deg, const int* __restrict__ partial,
                           int* __restrict__ row_start, int n) {
  __shared__ int lds[256];
  const int tid = threadIdx.x;
  const int base = blockIdx.x * SCAN_TILE + tid * 4;
  int d[4];
  int s = 0;
#pragma unroll
  for (int j = 0; j < 4; ++j) {
    int i = base + j;
    d[j] = (i < n) ? deg[i] : 0;
    s += d[j];
  }
  lds[tid] = s;
  __syncthreads();
  for (int off = 1; off < 256; off <<= 1) {
    int t = (tid >= off) ? lds[tid - off] : 0;
    __syncthreads();
    lds[tid] += t;
    __syncthreads();
  }
  int pre = partial[blockIdx.x] + lds[tid] - s;
#pragma unroll
  for (int j = 0; j < 4; ++j) {
    int i = base + j;
    if (i < n) {
      row_start[i] = pre;
      pre += d[j];
    }
  }
}

__global__ void fill_kernel(const int* __restrict__ src, const int* __restrict__ dst,
                            const int* __restrict__ row_start, int* __restrict__ cursor,
                            int* __restrict__ esrc, int E) {
  int i = blockIdx.x * blockDim.x + threadIdx.x;
  if (i < E) {
    int d = dst[i];
    int pos = atomicAdd(&cursor[d], 1);
    esrc[row_start[d] + pos] = src[i];
  }
}

// ----------------------------------------------------- mean aggregation (bf16 I/O)
// 16 lanes per node, 4 nodes per wave, 16 B per lane: lane fl owns features [8fl, 8fl+8)
__global__ void aggregate_bf16(const unsigned short* __restrict__ h, const int* __restrict__ row_start,
                               const int* __restrict__ esrc, unsigned short* __restrict__ mean, int n) {
  const int t = blockIdx.x * blockDim.x + threadIdx.x;
  const int node = t >> 4;              // 16 lanes per node
  const int fl = threadIdx.x & 15;      // feature lane
  if (node >= n) return;
  const int s0 = row_start[node], s1 = row_start[node + 1];
  float acc[8] = {0.f, 0.f, 0.f, 0.f, 0.f, 0.f, 0.f, 0.f};
  for (int e = s0; e < s1; ++e) {
    int s = esrc[e];
    uint4 raw = *(const uint4*)(h + (size_t)s * D + fl * 8);
    acc[0] += bf16_lo(raw.x); acc[1] += bf16_hi(raw.x);
    acc[2] += bf16_lo(raw.y); acc[3] += bf16_hi(raw.y);
    acc[4] += bf16_lo(raw.z); acc[5] += bf16_hi(raw.z);
    acc[6] += bf16_lo(raw.w); acc[7] += bf16_hi(raw.w);
  }
  const float inv = 1.0f / (float)max(s1 - s0, 1);
  uint4 o;
  o.x = (unsigned)f32_to_bf16(acc[0] * inv) | ((unsigned)f32_to_bf16(acc[1] * inv) << 16);
  o.y = (unsigned)f32_to_bf16(acc[2] * inv) | ((unsigned)f32_to_bf16(acc[3] * inv) << 16);
  o.z = (unsigned)f32_to_bf16(acc[4] * inv) | ((unsigned)f32_to_bf16(acc[5] * inv) << 16);
  o.w = (unsigned)f32_to_bf16(acc[6] * inv) | ((unsigned)f32_to_bf16(acc[7] * inv) << 16);
  *(uint4*)(mean + (size_t)node * D + fl * 8) = o;
}

// ----------------------------------------------------- MFMA bf16 GEMM
// out[M,128] = in0 @ W0 (+ in1 @ W1) + bias.  Wt transposed [n][k] bf16.
// 256 thr = 4 waves; wave computes 16 rows x 128 cols, K = NCHUNK*128.
template <int NCHUNK, bool FP32OUT>
__global__ __launch_bounds__(256) void gemm_mfma(
    const unsigned short* __restrict__ in0, const unsigned short* __restrict__ in1,
    const unsigned short* __restrict__ Wt0, const unsigned short* __restrict__ Wt1,
    const float* __restrict__ bias, void* __restrict__ out, int M) {
  const int lane = threadIdx.x & 63;
  const int wave = threadIdx.x >> 6;
  const int m0 = blockIdx.x * 64 + wave * 16;
  const int row = lane & 15;
  const int q = lane >> 4;
  const int mload = min(m0 + row, M - 1);

  bf16x8 afrag[NCHUNK * 4];
#pragma unroll
  for (int s = 0; s < NCHUNK * 4; ++s) {
    const unsigned short* src = (NCHUNK == 2 && s >= 4) ? in1 : in0;
    afrag[s] = *reinterpret_cast<const bf16x8*>(src + (size_t)mload * D + (s & 3) * 32 + q * 8);
  }
  f32x4 acc[8];
#pragma unroll
  for (int t = 0; t < 8; ++t) acc[t] = (f32x4){0.f, 0.f, 0.f, 0.f};

#pragma unroll
  for (int t = 0; t < 8; ++t) {
    const int n = t * 16 + row;
#pragma unroll
    for (int s = 0; s < NCHUNK * 4; ++s) {
      const unsigned short* wb = (NCHUNK == 2 && s >= 4) ? Wt1 : Wt0;
      bf16x8 b = *reinterpret_cast<const bf16x8*>(wb + (size_t)n * D + (s & 3) * 32 + q * 8);
      acc[t] = __builtin_amdgcn_mfma_f32_16x16x32_bf16(afrag[s], b, acc[t], 0, 0, 0);
    }
  }

#pragma unroll
  for (int t = 0; t < 8; ++t) {
    const int col = t * 16 + row;
    const float bv = bias ? bias[col] : 0.f;
#pragma unroll
    for (int r = 0; r < 4; ++r) {
      int m = m0 + q * 4 + r;
      if (m < M) {
        float v = acc[t][r] + bv;
        if (FP32OUT)
          ((float*)out)[(size_t)m * D + col] = v;
        else
          ((unsigned short*)out)[(size_t)m * D + col] = f32_to_bf16(v);
      }
    }
  }
}

// ----------------------------------------------------- per-edge MLP score (bf16 A/B)
// score[e] = relu(A[s] + B[d]) . Wp2 + bp2   (bp1 folded into A)
// 16 lanes per edge, 4 edges per wave, 16 B per lane
__global__ void edge_score_bf16(const unsigned short* __restrict__ A, const unsigned short* __restrict__ B,
                                const int* __restrict__ s, const int* __restrict__ d,
                                const float* __restrict__ Wp2, const float* __restrict__ bp2,
                                float* __restrict__ out, int E) {
  const int t = blockIdx.x * blockDim.x + threadIdx.x;
  const int e = t >> 4;                 // 16 lanes per edge
  const int fl = threadIdx.x & 15;
  if (e >= E) return;
  const int si = s[e], di = d[e];
  uint4 ra = *(const uint4*)(A + (size_t)si * D + fl * 8);
  uint4 rb = *(const uint4*)(B + (size_t)di * D + fl * 8);
  float4 w0 = *(const float4*)(Wp2 + fl * 8);
  float4 w1 = *(const float4*)(Wp2 + fl * 8 + 4);
  float x0 = bf16_lo(ra.x) + bf16_lo(rb.x);
  float x1 = bf16_hi(ra.x) + bf16_hi(rb.x);
  float x2 = bf16_lo(ra.y) + bf16_lo(rb.y);
  float x3 = bf16_hi(ra.y) + bf16_hi(rb.y);
  float x4 = bf16_lo(ra.z) + bf16_lo(rb.z);
  float x5 = bf16_hi(ra.z) + bf16_hi(rb.z);
  float x6 = bf16_lo(ra.w) + bf16_lo(rb.w);
  float x7 = bf16_hi(ra.w) + bf16_hi(rb.w);
  float p = fmaxf(x0, 0.f) * w0.x + fmaxf(x1, 0.f) * w0.y +
            fmaxf(x2, 0.f) * w0.z + fmaxf(x3, 0.f) * w0.w +
            fmaxf(x4, 0.f) * w1.x + fmaxf(x5, 0.f) * w1.y +
            fmaxf(x6, 0.f) * w1.z + fmaxf(x7, 0.f) * w1.w;
  // reduce over the 16-lane group (xor masks < 16 stay within the group)
  p += __shfl_xor(p, 1);
  p += __shfl_xor(p, 2);
  p += __shfl_xor(p, 4);
  p += __shfl_xor(p, 8);
  if (fl == 0) out[e] = p + bp2[0];
}

// ---------------------------------------------------------------- launcher
extern "C" void kernel_launch(void* const* d_in, const int* in_sizes, int n_in,
                              void* d_out, int out_size, void* d_ws, size_t ws_size,
                              hipStream_t stream) {
  const float* x = (const float*)d_in[0];
  const int* src = (const int*)d_in[1];
  const int* dst = (const int*)d_in[2];
  const int* nsrc = (const int*)d_in[3];
  const int* ndst = (const int*)d_in[4];
  const float* Ws1 = (const float*)d_in[5];
  const float* Wn1 = (const float*)d_in[6];
  const float* b1 = (const float*)d_in[7];
  const float* Ws2 = (const float*)d_in[8];
  const float* Wn2 = (const float*)d_in[9];
  const float* b2 = (const float*)d_in[10];
  const float* Ws3 = (const float*)d_in[11];
  const float* Wn3 = (const float*)d_in[12];
  const float* b3 = (const float*)d_in[13];
  const float* Wp1 = (const float*)d_in[14];
  const float* bp1 = (const float*)d_in[15];
  const float* Wp2 = (const float*)d_in[16];
  const float* bp2 = (const float*)d_in[17];
  float* out = (float*)d_out;

  char* ws = (char*)d_ws;
  size_t off = 0;
  auto alloc = [&](size_t bytes) -> void* {
    void* p = ws + off;
    off += (bytes + 255) & ~(size_t)255;
    return p;
  };
  const size_t NODE_F32 = sizeof(float) * (size_t)N_NODES * D;  // 51.2 MB
  char* region0 = (char*)alloc(NODE_F32);   // bf16 xb | bf16 mean
  char* region1 = (char*)alloc(NODE_F32);   // bf16 h_A | bf16 h_B
  char* region2 = (char*)alloc(NODE_F32);   // bf16 A | bf16 B
  int* row_start = (int*)alloc(sizeof(int) * (N_NODES + 1));
  int* deg = (int*)alloc(sizeof(int) * N_NODES * 2);
  int* cursor = deg + N_NODES;
  int* esrc = (int*)alloc(sizeof(int) * N_EDGES);
  int* partial = (int*)alloc(sizeof(int) * 128);
  unsigned short* wt = (unsigned short*)alloc(sizeof(unsigned short) * 8 * D * D);
  (void)ws_size;

  unsigned short* xb = (unsigned short*)region0;
  unsigned short* meanb = xb + (size_t)N_NODES * D;
  unsigned short* hA = (unsigned short*)region1;
  unsigned short* hB = hA + (size_t)N_NODES * D;
  unsigned short* Ab = (unsigned short*)region2;
  unsigned short* Bb = Ab + (size_t)N_NODES * D;

  // ---- conversions
  f32_to_bf16_vec<<<(N_NODES * D / 4 + 255) / 256, 256, 0, stream>>>(x, xb, N_NODES * D / 4);
  transpose_w<<<512, 256, 0, stream>>>(Ws1, Wn1, Ws2, Wn2, Ws3, Wn3, Wp1, Wp1 + D * D, wt);

  // ---- CSR build (reused by all 3 layers)
  zero_i32<<<(2 * N_NODES + 255) / 256, 256, 0, stream>>>(deg, 2 * N_NODES);
  hist_kernel<<<(N_EDGES + 255) / 256, 256, 0, stream>>>(dst, deg, N_EDGES);
  scan_blocksum<<<SCAN_BLOCKS, 256, 0, stream>>>(deg, partial, N_NODES);
  scan_offsets<<<1, 128, 0, stream>>>(partial, row_start, SCAN_BLOCKS, N_NODES);
  scan_final<<<SCAN_BLOCKS, 256, 0, stream>>>(deg, partial, row_start, N_NODES);
  fill_kernel<<<(N_EDGES + 255) / 256, 256, 0, stream>>>(src, dst, row_start, cursor, esrc, N_EDGES);

  const int aggBlocks = (N_NODES * 16 + 255) / 256;   // 16 lanes/node
  const int gemmBlocks = (N_NODES + 63) / 64;
  const int edgeBlocks = (N_EDGES * 16) / 256;        // 16 lanes/edge

  // ---- layer 1
  aggregate_bf16<<<aggBlocks, 256, 0, stream>>>(xb, row_start, esrc, meanb, N_NODES);
  gemm_mfma<2, false><<<gemmBlocks, 256, 0, stream>>>(xb, meanb, wt, wt + 16384, b1, hA, N_NODES);
  // ---- layer 2
  aggregate_bf16<<<aggBlocks, 256, 0, stream>>>(hA, row_start, esrc, meanb, N_NODES);
  gemm_mfma<2, false><<<gemmBlocks, 256, 0, stream>>>(hA, meanb, wt + 2 * 16384, wt + 3 * 16384, b2, hB, N_NODES);
  // ---- layer 3
  aggregate_bf16<<<aggBlocks, 256, 0, stream>>>(hB, row_start, esrc, meanb, N_NODES);
  gemm_mfma<2, false><<<gemmBlocks, 256, 0, stream>>>(hB, meanb, wt + 4 * 16384, wt + 5 * 16384, b3, hA, N_NODES);
  // ---- predictor precompute: A = h3@Wp1_top + bp1 (bf16), B = h3@Wp1_bot (bf16)
  gemm_mfma<1, false><<<gemmBlocks, 256, 0, stream>>>(hA, nullptr, wt + 6 * 16384, nullptr, bp1, Ab, N_NODES);
  gemm_mfma<1, false><<<gemmBlocks, 256, 0, stream>>>(hA, nullptr, wt + 7 * 16384, nullptr, nullptr, Bb, N_NODES);
  // ---- edge scores
  edge_score_bf16<<<edgeBlocks, 256, 0, stream>>>(Ab, Bb, src, dst, Wp2, bp2, out, N_EDGES);
  edge_score_bf16<<<edgeBlocks, 256, 0, stream>>>(Ab, Bb, nsrc, ndst, Wp2, bp2, out + N_EDGES, N_EDGES);
}

// Round 6
// 529.494 us; speedup vs baseline: 2.3180x; 1.2603x over previous
//
#include <hip/hip_runtime.h>

#define N_NODES 100000
#define N_EDGES 640000
#define D 128
#define SCAN_TILE 1024
#define SCAN_BLOCKS ((N_NODES + SCAN_TILE - 1) / SCAN_TILE)  // 98

typedef __attribute__((ext_vector_type(8))) short bf16x8;   // 8 bf16 = 4 VGPRs
typedef __attribute__((ext_vector_type(4))) float f32x4;

__device__ __forceinline__ unsigned short f32_to_bf16(float f) {
  union { float f; unsigned int u; } v; v.f = f;
  unsigned int u = v.u;
  unsigned int r = (u + 0x7fffu + ((u >> 16) & 1u)) >> 16;  // RNE
  return (unsigned short)r;
}
__device__ __forceinline__ float bf16_lo(unsigned int u) { return __uint_as_float(u << 16); }
__device__ __forceinline__ float bf16_hi(unsigned int u) { return __uint_as_float(u & 0xffff0000u); }

// ---------------------------------------------------------------- utilities
__global__ void zero_i32(int* __restrict__ p, int n) {
  int i = blockIdx.x * blockDim.x + threadIdx.x;
  if (i < n) p[i] = 0;
}

// fp32 -> bf16, 4 elems/thread
__global__ void f32_to_bf16_vec(const float* __restrict__ in, unsigned short* __restrict__ out, int n4) {
  int i = blockIdx.x * blockDim.x + threadIdx.x;
  if (i < n4) {
    float4 v = ((const float4*)in)[i];
    ushort4 o;
    o.x = f32_to_bf16(v.x); o.y = f32_to_bf16(v.y);
    o.z = f32_to_bf16(v.z); o.w = f32_to_bf16(v.w);
    ((ushort4*)out)[i] = o;
  }
}

// 8 weight matrices [128x128] fp32 row-major [k][n] -> bf16 transposed Wt[n][k]
__global__ void transpose_w(const float* __restrict__ W0, const float* __restrict__ W1,
                            const float* __restrict__ W2, const float* __restrict__ W3,
                            const float* __restrict__ W4, const float* __restrict__ W5,
                            const float* __restrict__ W6, const float* __restrict__ W7,
                            unsigned short* __restrict__ wt) {
  int id = blockIdx.x * 256 + threadIdx.x;  // 512 blocks x 256 = 131072
  int mat = id >> 14;
  int rem = id & 16383;
  int n = rem >> 7, k = rem & 127;
  const float* Wm = mat < 4 ? (mat < 2 ? (mat == 0 ? W0 : W1) : (mat == 2 ? W2 : W3))
                            : (mat < 6 ? (mat == 4 ? W4 : W5) : (mat == 6 ? W6 : W7));
  wt[id] = f32_to_bf16(Wm[k * D + n]);
}

// ------------------------------------------------------------- CSR building
__global__ void hist_kernel(const int* __restrict__ dst, int* __restrict__ deg, int E) {
  int i = blockIdx.x * blockDim.x + threadIdx.x;
  if (i < E) atomicAdd(&deg[dst[i]], 1);
}

__global__ void scan_blocksum(const int* __restrict__ deg, int* __restrict__ partial, int n) {
  __shared__ int lds[256];
  const int tid = threadIdx.x;
  const int base = blockIdx.x * SCAN_TILE + tid * 4;
  int s = 0;
#pragma unroll
  for (int j = 0; j < 4; ++j) {
    int i = base + j;
    if (i < n) s += deg[i];
  }
  lds[tid] = s;
  __syncthreads();
  for (int off = 128; off > 0; off >>= 1) {
    if (tid < off) lds[tid] += lds[tid + off];
    __syncthreads();
  }
  if (tid == 0) partial[blockIdx.x] = lds[0];
}

__global__ void scan_offsets(int* __restrict__ partial, int* __restrict__ row_start, int nb, int n) {
  __shared__ int lds[128];
  const int tid = threadIdx.x;
  int v = (tid < nb) ? partial[tid] : 0;
  lds[tid] = v;
  __syncthreads();
  for (int off = 1; off < 128; off <<= 1) {
    int t = (tid >= off) ? lds[tid - off] : 0;
    __syncthreads();
    lds[tid] += t;
    __syncthreads();
  }
  if (tid < nb) partial[tid] = (tid == 0) ? 0 : lds[tid - 1];
  if (tid == 0) row_start[n] = lds[nb - 1];
}

__global__ void scan_final(const int* __restrict__ deg, const int* __restrict__ partial,
                           int* __restrict__ row_start, int n) {
  __shared__ int lds[256];
  const int tid = threadIdx.x;
  const int base = blockIdx.x * SCAN_TILE + tid * 4;
  int d[4];
  int s = 0;
#pragma unroll
  for (int j = 0; j < 4; ++j) {
    int i = base + j;
    d[j] = (i < n) ? deg[i] : 0;
    s += d[j];
  }
  lds[tid] = s;
  __syncthreads();
  for (int off = 1; off < 256; off <<= 1) {
    int t = (tid >= off) ? lds[tid - off] : 0;
    __syncthreads();
    lds[tid] += t;
    __syncthreads();
  }
  int pre = partial[blockIdx.x] + lds[tid] - s;
#pragma unroll
  for (int j = 0; j < 4; ++j) {
    int i = base + j;
    if (i < n) {
      row_start[i] = pre;
      pre += d[j];
    }
  }
}

__global__ void fill_kernel(const int* __restrict__ src, const int* __restrict__ dst,
                            const int* __restrict__ row_start, int* __restrict__ cursor,
                            int* __restrict__ esrc, int E) {
  int i = blockIdx.x * blockDim.x + threadIdx.x;
  if (i < E) {
    int d = dst[i];
    int pos = atomicAdd(&cursor[d], 1);
    esrc[row_start[d] + pos] = src[i];
  }
}

// ----------------------------------------------------- mean aggregation (bf16 I/O)
// 16 lanes per node, 4 nodes per wave, 16 B per lane: lane fl owns features [8fl, 8fl+8)
__global__ void aggregate_bf16(const unsigned short* __restrict__ h, const int* __restrict__ row_start,
                               const int* __restrict__ esrc, unsigned short* __restrict__ mean, int n) {
  const int t = blockIdx.x * blockDim.x + threadIdx.x;
  const int node = t >> 4;              // 16 lanes per node
  const int fl = threadIdx.x & 15;      // feature lane
  if (node >= n) return;
  const int s0 = row_start[node], s1 = row_start[node + 1];
  float acc[8] = {0.f, 0.f, 0.f, 0.f, 0.f, 0.f, 0.f, 0.f};
  for (int e = s0; e < s1; ++e) {
    int s = esrc[e];
    uint4 raw = *(const uint4*)(h + (size_t)s * D + fl * 8);
    acc[0] += bf16_lo(raw.x); acc[1] += bf16_hi(raw.x);
    acc[2] += bf16_lo(raw.y); acc[3] += bf16_hi(raw.y);
    acc[4] += bf16_lo(raw.z); acc[5] += bf16_hi(raw.z);
    acc[6] += bf16_lo(raw.w); acc[7] += bf16_hi(raw.w);
  }
  const float inv = 1.0f / (float)max(s1 - s0, 1);
  uint4 o;
  o.x = (unsigned)f32_to_bf16(acc[0] * inv) | ((unsigned)f32_to_bf16(acc[1] * inv) << 16);
  o.y = (unsigned)f32_to_bf16(acc[2] * inv) | ((unsigned)f32_to_bf16(acc[3] * inv) << 16);
  o.z = (unsigned)f32_to_bf16(acc[4] * inv) | ((unsigned)f32_to_bf16(acc[5] * inv) << 16);
  o.w = (unsigned)f32_to_bf16(acc[6] * inv) | ((unsigned)f32_to_bf16(acc[7] * inv) << 16);
  *(uint4*)(mean + (size_t)node * D + fl * 8) = o;
}

// ----------------------------------------------------- MFMA bf16 GEMM (LDS-staged weights)
// out[M,128] = in0 @ W0 (+ in1 @ W1) + bias.  Wt transposed [n][k] bf16.
// 256 thr = 4 waves; wave computes 16 rows x 128 cols, K = NCHUNK*128.
// Weights staged in LDS (row pad +8 shorts -> <=2-way bank conflicts, free).
// Loop order s-outer / t-inner: 8 independent MFMA chains per s-step (ILP),
// vs old t-outer which serialized load->mfma 64 times (VGPR=52, 27k cyc/wave).
template <int NCHUNK, bool FP32OUT>
__global__ __launch_bounds__(256) void gemm_mfma(
    const unsigned short* __restrict__ in0, const unsigned short* __restrict__ in1,
    const unsigned short* __restrict__ Wt0, const unsigned short* __restrict__ Wt1,
    const float* __restrict__ bias, void* __restrict__ out, int M) {
  __shared__ unsigned short wl[128][136];  // 34.8 KB
  const int tid = threadIdx.x;
  const int lane = tid & 63;
  const int wave = tid >> 6;
  const int m0 = blockIdx.x * 64 + wave * 16;
  const int row = lane & 15;
  const int q = lane >> 4;
  const int mload = min(m0 + row, M - 1);

  // A fragments for all chunks upfront (independent HBM loads, deep MLP)
  bf16x8 afrag[NCHUNK * 4];
#pragma unroll
  for (int s = 0; s < NCHUNK * 4; ++s) {
    const unsigned short* srcp = (NCHUNK == 2 && s >= 4) ? in1 : in0;
    afrag[s] = *reinterpret_cast<const bf16x8*>(srcp + (size_t)mload * D + (s & 3) * 32 + q * 8);
  }
  f32x4 acc[8];
#pragma unroll
  for (int t = 0; t < 8; ++t) acc[t] = (f32x4){0.f, 0.f, 0.f, 0.f};

  for (int c = 0; c < NCHUNK; ++c) {
    const unsigned short* wsrc = (c == 0) ? Wt0 : Wt1;
    if (c) __syncthreads();  // protect LDS buffer reuse
    // stage 128x128 bf16 (32 KB): 2048 16B segments, 8 per thread, fully coalesced
#pragma unroll
    for (int i = 0; i < 8; ++i) {
      int seg = i * 256 + tid;
      int r = seg >> 4;
      int o = (seg & 15) * 8;
      *reinterpret_cast<bf16x8*>(&wl[r][o]) =
          *reinterpret_cast<const bf16x8*>(wsrc + r * D + o);
    }
    __syncthreads();
#pragma unroll
    for (int s = 0; s < 4; ++s) {
#pragma unroll
      for (int t = 0; t < 8; ++t) {
        const int n = t * 16 + row;
        bf16x8 b = *reinterpret_cast<const bf16x8*>(&wl[n][s * 32 + q * 8]);
        acc[t] = __builtin_amdgcn_mfma_f32_16x16x32_bf16(afrag[c * 4 + s], b, acc[t], 0, 0, 0);
      }
    }
  }

#pragma unroll
  for (int t = 0; t < 8; ++t) {
    const int col = t * 16 + row;
    const float bv = bias ? bias[col] : 0.f;
#pragma unroll
    for (int r = 0; r < 4; ++r) {
      int m = m0 + q * 4 + r;
      if (m < M) {
        float v = acc[t][r] + bv;
        if (FP32OUT)
          ((float*)out)[(size_t)m * D + col] = v;
        else
          ((unsigned short*)out)[(size_t)m * D + col] = f32_to_bf16(v);
      }
    }
  }
}

// ----------------------------------------------------- per-edge MLP score (bf16 A/B)
// score[e] = relu(A[s] + B[d]) . Wp2 + bp2   (bp1 folded into A)
// 16 lanes per edge, 4 edges per wave, 16 B per lane
__global__ void edge_score_bf16(const unsigned short* __restrict__ A, const unsigned short* __restrict__ B,
                                const int* __restrict__ s, const int* __restrict__ d,
                                const float* __restrict__ Wp2, const float* __restrict__ bp2,
                                float* __restrict__ out, int E) {
  const int t = blockIdx.x * blockDim.x + threadIdx.x;
  const int e = t >> 4;                 // 16 lanes per edge
  const int fl = threadIdx.x & 15;
  if (e >= E) return;
  const int si = s[e], di = d[e];
  uint4 ra = *(const uint4*)(A + (size_t)si * D + fl * 8);
  uint4 rb = *(const uint4*)(B + (size_t)di * D + fl * 8);
  float4 w0 = *(const float4*)(Wp2 + fl * 8);
  float4 w1 = *(const float4*)(Wp2 + fl * 8 + 4);
  float x0 = bf16_lo(ra.x) + bf16_lo(rb.x);
  float x1 = bf16_hi(ra.x) + bf16_hi(rb.x);
  float x2 = bf16_lo(ra.y) + bf16_lo(rb.y);
  float x3 = bf16_hi(ra.y) + bf16_hi(rb.y);
  float x4 = bf16_lo(ra.z) + bf16_lo(rb.z);
  float x5 = bf16_hi(ra.z) + bf16_hi(rb.z);
  float x6 = bf16_lo(ra.w) + bf16_lo(rb.w);
  float x7 = bf16_hi(ra.w) + bf16_hi(rb.w);
  float p = fmaxf(x0, 0.f) * w0.x + fmaxf(x1, 0.f) * w0.y +
            fmaxf(x2, 0.f) * w0.z + fmaxf(x3, 0.f) * w0.w +
            fmaxf(x4, 0.f) * w1.x + fmaxf(x5, 0.f) * w1.y +
            fmaxf(x6, 0.f) * w1.z + fmaxf(x7, 0.f) * w1.w;
  // reduce over the 16-lane group (xor masks < 16 stay within the group)
  p += __shfl_xor(p, 1);
  p += __shfl_xor(p, 2);
  p += __shfl_xor(p, 4);
  p += __shfl_xor(p, 8);
  if (fl == 0) out[e] = p + bp2[0];
}

// ---------------------------------------------------------------- launcher
extern "C" void kernel_launch(void* const* d_in, const int* in_sizes, int n_in,
                              void* d_out, int out_size, void* d_ws, size_t ws_size,
                              hipStream_t stream) {
  const float* x = (const float*)d_in[0];
  const int* src = (const int*)d_in[1];
  const int* dst = (const int*)d_in[2];
  const int* nsrc = (const int*)d_in[3];
  const int* ndst = (const int*)d_in[4];
  const float* Ws1 = (const float*)d_in[5];
  const float* Wn1 = (const float*)d_in[6];
  const float* b1 = (const float*)d_in[7];
  const float* Ws2 = (const float*)d_in[8];
  const float* Wn2 = (const float*)d_in[9];
  const float* b2 = (const float*)d_in[10];
  const float* Ws3 = (const float*)d_in[11];
  const float* Wn3 = (const float*)d_in[12];
  const float* b3 = (const float*)d_in[13];
  const float* Wp1 = (const float*)d_in[14];
  const float* bp1 = (const float*)d_in[15];
  const float* Wp2 = (const float*)d_in[16];
  const float* bp2 = (const float*)d_in[17];
  float* out = (float*)d_out;

  char* ws = (char*)d_ws;
  size_t off = 0;
  auto alloc = [&](size_t bytes) -> void* {
    void* p = ws + off;
    off += (bytes + 255) & ~(size_t)255;
    return p;
  };
  const size_t NODE_F32 = sizeof(float) * (size_t)N_NODES * D;  // 51.2 MB
  char* region0 = (char*)alloc(NODE_F32);   // bf16 xb | bf16 mean
  char* region1 = (char*)alloc(NODE_F32);   // bf16 h_A | bf16 h_B
  char* region2 = (char*)alloc(NODE_F32);   // bf16 A | bf16 B
  int* row_start = (int*)alloc(sizeof(int) * (N_NODES + 1));
  int* deg = (int*)alloc(sizeof(int) * N_NODES * 2);
  int* cursor = deg + N_NODES;
  int* esrc = (int*)alloc(sizeof(int) * N_EDGES);
  int* partial = (int*)alloc(sizeof(int) * 128);
  unsigned short* wt = (unsigned short*)alloc(sizeof(unsigned short) * 8 * D * D);
  (void)ws_size;

  unsigned short* xb = (unsigned short*)region0;
  unsigned short* meanb = xb + (size_t)N_NODES * D;
  unsigned short* hA = (unsigned short*)region1;
  unsigned short* hB = hA + (size_t)N_NODES * D;
  unsigned short* Ab = (unsigned short*)region2;
  unsigned short* Bb = Ab + (size_t)N_NODES * D;

  // ---- conversions
  f32_to_bf16_vec<<<(N_NODES * D / 4 + 255) / 256, 256, 0, stream>>>(x, xb, N_NODES * D / 4);
  transpose_w<<<512, 256, 0, stream>>>(Ws1, Wn1, Ws2, Wn2, Ws3, Wn3, Wp1, Wp1 + D * D, wt);

  // ---- CSR build (reused by all 3 layers)
  zero_i32<<<(2 * N_NODES + 255) / 256, 256, 0, stream>>>(deg, 2 * N_NODES);
  hist_kernel<<<(N_EDGES + 255) / 256, 256, 0, stream>>>(dst, deg, N_EDGES);
  scan_blocksum<<<SCAN_BLOCKS, 256, 0, stream>>>(deg, partial, N_NODES);
  scan_offsets<<<1, 128, 0, stream>>>(partial, row_start, SCAN_BLOCKS, N_NODES);
  scan_final<<<SCAN_BLOCKS, 256, 0, stream>>>(deg, partial, row_start, N_NODES);
  fill_kernel<<<(N_EDGES + 255) / 256, 256, 0, stream>>>(src, dst, row_start, cursor, esrc, N_EDGES);

  const int aggBlocks = (N_NODES * 16 + 255) / 256;   // 16 lanes/node
  const int gemmBlocks = (N_NODES + 63) / 64;
  const int edgeBlocks = (N_EDGES * 16) / 256;        // 16 lanes/edge

  // ---- layer 1
  aggregate_bf16<<<aggBlocks, 256, 0, stream>>>(xb, row_start, esrc, meanb, N_NODES);
  gemm_mfma<2, false><<<gemmBlocks, 256, 0, stream>>>(xb, meanb, wt, wt + 16384, b1, hA, N_NODES);
  // ---- layer 2
  aggregate_bf16<<<aggBlocks, 256, 0, stream>>>(hA, row_start, esrc, meanb, N_NODES);
  gemm_mfma<2, false><<<gemmBlocks, 256, 0, stream>>>(hA, meanb, wt + 2 * 16384, wt + 3 * 16384, b2, hB, N_NODES);
  // ---- layer 3
  aggregate_bf16<<<aggBlocks, 256, 0, stream>>>(hB, row_start, esrc, meanb, N_NODES);
  gemm_mfma<2, false><<<gemmBlocks, 256, 0, stream>>>(hB, meanb, wt + 4 * 16384, wt + 5 * 16384, b3, hA, N_NODES);
  // ---- predictor precompute: A = h3@Wp1_top + bp1 (bf16), B = h3@Wp1_bot (bf16)
  gemm_mfma<1, false><<<gemmBlocks, 256, 0, stream>>>(hA, nullptr, wt + 6 * 16384, nullptr, bp1, Ab, N_NODES);
  gemm_mfma<1, false><<<gemmBlocks, 256, 0, stream>>>(hA, nullptr, wt + 7 * 16384, nullptr, nullptr, Bb, N_NODES);
  // ---- edge scores
  edge_score_bf16<<<edgeBlocks, 256, 0, stream>>>(Ab, Bb, src, dst, Wp2, bp2, out, N_EDGES);
  edge_score_bf16<<<edgeBlocks, 256, 0, stream>>>(Ab, Bb, nsrc, ndst, Wp2, bp2, out + N_EDGES, N_EDGES);
}

// Round 7
// 507.507 us; speedup vs baseline: 2.4184x; 1.0433x over previous
//
#include <hip/hip_runtime.h>

#define N_NODES 100000
#define N_EDGES 640000
#define D 128
#define SCAN_TILE 1024
#define SCAN_BLOCKS ((N_NODES + SCAN_TILE - 1) / SCAN_TILE)  // 98

typedef __attribute__((ext_vector_type(8))) short bf16x8;   // 8 bf16 = 4 VGPRs
typedef __attribute__((ext_vector_type(4))) float f32x4;

__device__ __forceinline__ unsigned short f32_to_bf16(float f) {
  union { float f; unsigned int u; } v; v.f = f;
  unsigned int u = v.u;
  unsigned int r = (u + 0x7fffu + ((u >> 16) & 1u)) >> 16;  // RNE
  return (unsigned short)r;
}
__device__ __forceinline__ float bf16_lo(unsigned int u) { return __uint_as_float(u << 16); }
__device__ __forceinline__ float bf16_hi(unsigned int u) { return __uint_as_float(u & 0xffff0000u); }

// ---------------------------------------------------------------- utilities
__global__ void zero_i32(int* __restrict__ p, int n) {
  int i = blockIdx.x * blockDim.x + threadIdx.x;
  if (i < n) p[i] = 0;
}

// fp32 -> bf16, 4 elems/thread
__global__ void f32_to_bf16_vec(const float* __restrict__ in, unsigned short* __restrict__ out, int n4) {
  int i = blockIdx.x * blockDim.x + threadIdx.x;
  if (i < n4) {
    float4 v = ((const float4*)in)[i];
    ushort4 o;
    o.x = f32_to_bf16(v.x); o.y = f32_to_bf16(v.y);
    o.z = f32_to_bf16(v.z); o.w = f32_to_bf16(v.w);
    ((ushort4*)out)[i] = o;
  }
}

// 8 weight matrices [128x128] fp32 row-major [k][n] -> bf16 transposed Wt[n][k]
__global__ void transpose_w(const float* __restrict__ W0, const float* __restrict__ W1,
                            const float* __restrict__ W2, const float* __restrict__ W3,
                            const float* __restrict__ W4, const float* __restrict__ W5,
                            const float* __restrict__ W6, const float* __restrict__ W7,
                            unsigned short* __restrict__ wt) {
  int id = blockIdx.x * 256 + threadIdx.x;  // 512 blocks x 256 = 131072
  int mat = id >> 14;
  int rem = id & 16383;
  int n = rem >> 7, k = rem & 127;
  const float* Wm = mat < 4 ? (mat < 2 ? (mat == 0 ? W0 : W1) : (mat == 2 ? W2 : W3))
                            : (mat < 6 ? (mat == 4 ? W4 : W5) : (mat == 6 ? W6 : W7));
  wt[id] = f32_to_bf16(Wm[k * D + n]);
}

// ------------------------------------------------------------- CSR building
__global__ void hist_kernel(const int* __restrict__ dst, int* __restrict__ deg, int E) {
  int i = blockIdx.x * blockDim.x + threadIdx.x;
  if (i < E) atomicAdd(&deg[dst[i]], 1);
}

__global__ void scan_blocksum(const int* __restrict__ deg, int* __restrict__ partial, int n) {
  __shared__ int lds[256];
  const int tid = threadIdx.x;
  const int base = blockIdx.x * SCAN_TILE + tid * 4;
  int s = 0;
#pragma unroll
  for (int j = 0; j < 4; ++j) {
    int i = base + j;
    if (i < n) s += deg[i];
  }
  lds[tid] = s;
  __syncthreads();
  for (int off = 128; off > 0; off >>= 1) {
    if (tid < off) lds[tid] += lds[tid + off];
    __syncthreads();
  }
  if (tid == 0) partial[blockIdx.x] = lds[0];
}

__global__ void scan_offsets(int* __restrict__ partial, int* __restrict__ row_start, int nb, int n) {
  __shared__ int lds[128];
  const int tid = threadIdx.x;
  int v = (tid < nb) ? partial[tid] : 0;
  lds[tid] = v;
  __syncthreads();
  for (int off = 1; off < 128; off <<= 1) {
    int t = (tid >= off) ? lds[tid - off] : 0;
    __syncthreads();
    lds[tid] += t;
    __syncthreads();
  }
  if (tid < nb) partial[tid] = (tid == 0) ? 0 : lds[tid - 1];
  if (tid == 0) row_start[n] = lds[nb - 1];
}

__global__ void scan_final(const int* __restrict__ deg, const int* __restrict__ partial,
                           int* __restrict__ row_start, int n) {
  __shared__ int lds[256];
  const int tid = threadIdx.x;
  const int base = blockIdx.x * SCAN_TILE + tid * 4;
  int d[4];
  int s = 0;
#pragma unroll
  for (int j = 0; j < 4; ++j) {
    int i = base + j;
    d[j] = (i < n) ? deg[i] : 0;
    s += d[j];
  }
  lds[tid] = s;
  __syncthreads();
  for (int off = 1; off < 256; off <<= 1) {
    int t = (tid >= off) ? lds[tid - off] : 0;
    __syncthreads();
    lds[tid] += t;
    __syncthreads();
  }
  int pre = partial[blockIdx.x] + lds[tid] - s;
#pragma unroll
  for (int j = 0; j < 4; ++j) {
    int i = base + j;
    if (i < n) {
      row_start[i] = pre;
      pre += d[j];
    }
  }
}

__global__ void fill_kernel(const int* __restrict__ src, const int* __restrict__ dst,
                            const int* __restrict__ row_start, int* __restrict__ cursor,
                            int* __restrict__ esrc, int E) {
  int i = blockIdx.x * blockDim.x + threadIdx.x;
  if (i < E) {
    int d = dst[i];
    int pos = atomicAdd(&cursor[d], 1);
    esrc[row_start[d] + pos] = src[i];
  }
}

// ----------------------------------------------------- mean aggregation (bf16 I/O)
// 16 lanes per node, 4 nodes per wave, 16 B per lane: lane fl owns features [8fl, 8fl+8)
// Edge loop unrolled x4: 4 independent row gathers in flight per group (MLP).
__global__ void aggregate_bf16(const unsigned short* __restrict__ h, const int* __restrict__ row_start,
                               const int* __restrict__ esrc, unsigned short* __restrict__ mean, int n) {
  const int t = blockIdx.x * blockDim.x + threadIdx.x;
  const int node = t >> 4;              // 16 lanes per node
  const int fl = threadIdx.x & 15;      // feature lane
  if (node >= n) return;
  const int s0 = row_start[node], s1 = row_start[node + 1];
  float acc[8] = {0.f, 0.f, 0.f, 0.f, 0.f, 0.f, 0.f, 0.f};
  int e = s0;
  for (; e + 4 <= s1; e += 4) {
    int i0 = esrc[e], i1 = esrc[e + 1], i2 = esrc[e + 2], i3 = esrc[e + 3];
    uint4 r0 = *(const uint4*)(h + (size_t)i0 * D + fl * 8);
    uint4 r1 = *(const uint4*)(h + (size_t)i1 * D + fl * 8);
    uint4 r2 = *(const uint4*)(h + (size_t)i2 * D + fl * 8);
    uint4 r3 = *(const uint4*)(h + (size_t)i3 * D + fl * 8);
    acc[0] += bf16_lo(r0.x); acc[1] += bf16_hi(r0.x);
    acc[2] += bf16_lo(r0.y); acc[3] += bf16_hi(r0.y);
    acc[4] += bf16_lo(r0.z); acc[5] += bf16_hi(r0.z);
    acc[6] += bf16_lo(r0.w); acc[7] += bf16_hi(r0.w);
    acc[0] += bf16_lo(r1.x); acc[1] += bf16_hi(r1.x);
    acc[2] += bf16_lo(r1.y); acc[3] += bf16_hi(r1.y);
    acc[4] += bf16_lo(r1.z); acc[5] += bf16_hi(r1.z);
    acc[6] += bf16_lo(r1.w); acc[7] += bf16_hi(r1.w);
    acc[0] += bf16_lo(r2.x); acc[1] += bf16_hi(r2.x);
    acc[2] += bf16_lo(r2.y); acc[3] += bf16_hi(r2.y);
    acc[4] += bf16_lo(r2.z); acc[5] += bf16_hi(r2.z);
    acc[6] += bf16_lo(r2.w); acc[7] += bf16_hi(r2.w);
    acc[0] += bf16_lo(r3.x); acc[1] += bf16_hi(r3.x);
    acc[2] += bf16_lo(r3.y); acc[3] += bf16_hi(r3.y);
    acc[4] += bf16_lo(r3.z); acc[5] += bf16_hi(r3.z);
    acc[6] += bf16_lo(r3.w); acc[7] += bf16_hi(r3.w);
  }
  for (; e < s1; ++e) {
    int s = esrc[e];
    uint4 raw = *(const uint4*)(h + (size_t)s * D + fl * 8);
    acc[0] += bf16_lo(raw.x); acc[1] += bf16_hi(raw.x);
    acc[2] += bf16_lo(raw.y); acc[3] += bf16_hi(raw.y);
    acc[4] += bf16_lo(raw.z); acc[5] += bf16_hi(raw.z);
    acc[6] += bf16_lo(raw.w); acc[7] += bf16_hi(raw.w);
  }
  const float inv = 1.0f / (float)max(s1 - s0, 1);
  uint4 o;
  o.x = (unsigned)f32_to_bf16(acc[0] * inv) | ((unsigned)f32_to_bf16(acc[1] * inv) << 16);
  o.y = (unsigned)f32_to_bf16(acc[2] * inv) | ((unsigned)f32_to_bf16(acc[3] * inv) << 16);
  o.z = (unsigned)f32_to_bf16(acc[4] * inv) | ((unsigned)f32_to_bf16(acc[5] * inv) << 16);
  o.w = (unsigned)f32_to_bf16(acc[6] * inv) | ((unsigned)f32_to_bf16(acc[7] * inv) << 16);
  *(uint4*)(mean + (size_t)node * D + fl * 8) = o;
}

// ----------------------------------------------------- MFMA bf16 GEMM (LDS-staged weights)
template <int NCHUNK, bool FP32OUT>
__global__ __launch_bounds__(256) void gemm_mfma(
    const unsigned short* __restrict__ in0, const unsigned short* __restrict__ in1,
    const unsigned short* __restrict__ Wt0, const unsigned short* __restrict__ Wt1,
    const float* __restrict__ bias, void* __restrict__ out, int M) {
  __shared__ unsigned short wl[128][136];  // 34.8 KB
  const int tid = threadIdx.x;
  const int lane = tid & 63;
  const int wave = tid >> 6;
  const int m0 = blockIdx.x * 64 + wave * 16;
  const int row = lane & 15;
  const int q = lane >> 4;
  const int mload = min(m0 + row, M - 1);

  bf16x8 afrag[NCHUNK * 4];
#pragma unroll
  for (int s = 0; s < NCHUNK * 4; ++s) {
    const unsigned short* srcp = (NCHUNK == 2 && s >= 4) ? in1 : in0;
    afrag[s] = *reinterpret_cast<const bf16x8*>(srcp + (size_t)mload * D + (s & 3) * 32 + q * 8);
  }
  f32x4 acc[8];
#pragma unroll
  for (int t = 0; t < 8; ++t) acc[t] = (f32x4){0.f, 0.f, 0.f, 0.f};

  for (int c = 0; c < NCHUNK; ++c) {
    const unsigned short* wsrc = (c == 0) ? Wt0 : Wt1;
    if (c) __syncthreads();
#pragma unroll
    for (int i = 0; i < 8; ++i) {
      int seg = i * 256 + tid;
      int r = seg >> 4;
      int o = (seg & 15) * 8;
      *reinterpret_cast<bf16x8*>(&wl[r][o]) =
          *reinterpret_cast<const bf16x8*>(wsrc + r * D + o);
    }
    __syncthreads();
#pragma unroll
    for (int s = 0; s < 4; ++s) {
#pragma unroll
      for (int t = 0; t < 8; ++t) {
        const int n = t * 16 + row;
        bf16x8 b = *reinterpret_cast<const bf16x8*>(&wl[n][s * 32 + q * 8]);
        acc[t] = __builtin_amdgcn_mfma_f32_16x16x32_bf16(afrag[c * 4 + s], b, acc[t], 0, 0, 0);
      }
    }
  }

#pragma unroll
  for (int t = 0; t < 8; ++t) {
    const int col = t * 16 + row;
    const float bv = bias ? bias[col] : 0.f;
#pragma unroll
    for (int r = 0; r < 4; ++r) {
      int m = m0 + q * 4 + r;
      if (m < M) {
        float v = acc[t][r] + bv;
        if (FP32OUT)
          ((float*)out)[(size_t)m * D + col] = v;
        else
          ((unsigned short*)out)[(size_t)m * D + col] = f32_to_bf16(v);
      }
    }
  }
}

// ----------------------------------------------------- fused pos+neg edge MLP score
// group g scores pos edge g AND neg edge g: 4 independent row gathers in flight.
// score = relu(A[s]+B[d]).Wp2 + bp2  (bp1 folded into A)
__global__ void edge_score_fused(const unsigned short* __restrict__ A, const unsigned short* __restrict__ B,
                                 const int* __restrict__ ps, const int* __restrict__ pd,
                                 const int* __restrict__ ns, const int* __restrict__ nd,
                                 const float* __restrict__ Wp2, const float* __restrict__ bp2,
                                 float* __restrict__ out, int E) {
  const int t = blockIdx.x * blockDim.x + threadIdx.x;
  const int e = t >> 4;                 // 16 lanes per edge pair
  const int fl = threadIdx.x & 15;
  if (e >= E) return;
  const int si = ps[e], di = pd[e];
  const int nsi = ns[e], ndi = nd[e];
  uint4 ra = *(const uint4*)(A + (size_t)si * D + fl * 8);
  uint4 rb = *(const uint4*)(B + (size_t)di * D + fl * 8);
  uint4 rna = *(const uint4*)(A + (size_t)nsi * D + fl * 8);
  uint4 rnb = *(const uint4*)(B + (size_t)ndi * D + fl * 8);
  float4 w0 = *(const float4*)(Wp2 + fl * 8);
  float4 w1 = *(const float4*)(Wp2 + fl * 8 + 4);

  float pp =
      fmaxf(bf16_lo(ra.x) + bf16_lo(rb.x), 0.f) * w0.x +
      fmaxf(bf16_hi(ra.x) + bf16_hi(rb.x), 0.f) * w0.y +
      fmaxf(bf16_lo(ra.y) + bf16_lo(rb.y), 0.f) * w0.z +
      fmaxf(bf16_hi(ra.y) + bf16_hi(rb.y), 0.f) * w0.w +
      fmaxf(bf16_lo(ra.z) + bf16_lo(rb.z), 0.f) * w1.x +
      fmaxf(bf16_hi(ra.z) + bf16_hi(rb.z), 0.f) * w1.y +
      fmaxf(bf16_lo(ra.w) + bf16_lo(rb.w), 0.f) * w1.z +
      fmaxf(bf16_hi(ra.w) + bf16_hi(rb.w), 0.f) * w1.w;
  float pn =
      fmaxf(bf16_lo(rna.x) + bf16_lo(rnb.x), 0.f) * w0.x +
      fmaxf(bf16_hi(rna.x) + bf16_hi(rnb.x), 0.f) * w0.y +
      fmaxf(bf16_lo(rna.y) + bf16_lo(rnb.y), 0.f) * w0.z +
      fmaxf(bf16_hi(rna.y) + bf16_hi(rnb.y), 0.f) * w0.w +
      fmaxf(bf16_lo(rna.z) + bf16_lo(rnb.z), 0.f) * w1.x +
      fmaxf(bf16_hi(rna.z) + bf16_hi(rnb.z), 0.f) * w1.y +
      fmaxf(bf16_lo(rna.w) + bf16_lo(rnb.w), 0.f) * w1.z +
      fmaxf(bf16_hi(rna.w) + bf16_hi(rnb.w), 0.f) * w1.w;

  pp += __shfl_xor(pp, 1);  pn += __shfl_xor(pn, 1);
  pp += __shfl_xor(pp, 2);  pn += __shfl_xor(pn, 2);
  pp += __shfl_xor(pp, 4);  pn += __shfl_xor(pn, 4);
  pp += __shfl_xor(pp, 8);  pn += __shfl_xor(pn, 8);
  if (fl == 0) {
    float b = bp2[0];
    out[e] = pp + b;
    out[E + e] = pn + b;
  }
}

// ---------------------------------------------------------------- launcher
extern "C" void kernel_launch(void* const* d_in, const int* in_sizes, int n_in,
                              void* d_out, int out_size, void* d_ws, size_t ws_size,
                              hipStream_t stream) {
  const float* x = (const float*)d_in[0];
  const int* src = (const int*)d_in[1];
  const int* dst = (const int*)d_in[2];
  const int* nsrc = (const int*)d_in[3];
  const int* ndst = (const int*)d_in[4];
  const float* Ws1 = (const float*)d_in[5];
  const float* Wn1 = (const float*)d_in[6];
  const float* b1 = (const float*)d_in[7];
  const float* Ws2 = (const float*)d_in[8];
  const float* Wn2 = (const float*)d_in[9];
  const float* b2 = (const float*)d_in[10];
  const float* Ws3 = (const float*)d_in[11];
  const float* Wn3 = (const float*)d_in[12];
  const float* b3 = (const float*)d_in[13];
  const float* Wp1 = (const float*)d_in[14];
  const float* bp1 = (const float*)d_in[15];
  const float* Wp2 = (const float*)d_in[16];
  const float* bp2 = (const float*)d_in[17];
  float* out = (float*)d_out;

  char* ws = (char*)d_ws;
  size_t off = 0;
  auto alloc = [&](size_t bytes) -> void* {
    void* p = ws + off;
    off += (bytes + 255) & ~(size_t)255;
    return p;
  };
  const size_t NODE_F32 = sizeof(float) * (size_t)N_NODES * D;  // 51.2 MB
  char* region0 = (char*)alloc(NODE_F32);   // bf16 xb | bf16 mean
  char* region1 = (char*)alloc(NODE_F32);   // bf16 h_A | bf16 h_B
  char* region2 = (char*)alloc(NODE_F32);   // bf16 A | bf16 B
  int* row_start = (int*)alloc(sizeof(int) * (N_NODES + 1));
  int* deg = (int*)alloc(sizeof(int) * N_NODES * 2);
  int* cursor = deg + N_NODES;
  int* esrc = (int*)alloc(sizeof(int) * N_EDGES);
  int* partial = (int*)alloc(sizeof(int) * 128);
  unsigned short* wt = (unsigned short*)alloc(sizeof(unsigned short) * 8 * D * D);
  (void)ws_size;

  unsigned short* xb = (unsigned short*)region0;
  unsigned short* meanb = xb + (size_t)N_NODES * D;
  unsigned short* hA = (unsigned short*)region1;
  unsigned short* hB = hA + (size_t)N_NODES * D;
  unsigned short* Ab = (unsigned short*)region2;
  unsigned short* Bb = Ab + (size_t)N_NODES * D;

  // ---- conversions
  f32_to_bf16_vec<<<(N_NODES * D / 4 + 255) / 256, 256, 0, stream>>>(x, xb, N_NODES * D / 4);
  transpose_w<<<512, 256, 0, stream>>>(Ws1, Wn1, Ws2, Wn2, Ws3, Wn3, Wp1, Wp1 + D * D, wt);

  // ---- CSR build (reused by all 3 layers)
  zero_i32<<<(2 * N_NODES + 255) / 256, 256, 0, stream>>>(deg, 2 * N_NODES);
  hist_kernel<<<(N_EDGES + 255) / 256, 256, 0, stream>>>(dst, deg, N_EDGES);
  scan_blocksum<<<SCAN_BLOCKS, 256, 0, stream>>>(deg, partial, N_NODES);
  scan_offsets<<<1, 128, 0, stream>>>(partial, row_start, SCAN_BLOCKS, N_NODES);
  scan_final<<<SCAN_BLOCKS, 256, 0, stream>>>(deg, partial, row_start, N_NODES);
  fill_kernel<<<(N_EDGES + 255) / 256, 256, 0, stream>>>(src, dst, row_start, cursor, esrc, N_EDGES);

  const int aggBlocks = (N_NODES * 16 + 255) / 256;   // 16 lanes/node
  const int gemmBlocks = (N_NODES + 63) / 64;
  const int edgeBlocks = (N_EDGES * 16) / 256;        // 16 lanes/edge-pair

  // ---- layer 1
  aggregate_bf16<<<aggBlocks, 256, 0, stream>>>(xb, row_start, esrc, meanb, N_NODES);
  gemm_mfma<2, false><<<gemmBlocks, 256, 0, stream>>>(xb, meanb, wt, wt + 16384, b1, hA, N_NODES);
  // ---- layer 2
  aggregate_bf16<<<aggBlocks, 256, 0, stream>>>(hA, row_start, esrc, meanb, N_NODES);
  gemm_mfma<2, false><<<gemmBlocks, 256, 0, stream>>>(hA, meanb, wt + 2 * 16384, wt + 3 * 16384, b2, hB, N_NODES);
  // ---- layer 3
  aggregate_bf16<<<aggBlocks, 256, 0, stream>>>(hB, row_start, esrc, meanb, N_NODES);
  gemm_mfma<2, false><<<gemmBlocks, 256, 0, stream>>>(hB, meanb, wt + 4 * 16384, wt + 5 * 16384, b3, hA, N_NODES);
  // ---- predictor precompute: A = h3@Wp1_top + bp1 (bf16), B = h3@Wp1_bot (bf16)
  gemm_mfma<1, false><<<gemmBlocks, 256, 0, stream>>>(hA, nullptr, wt + 6 * 16384, nullptr, bp1, Ab, N_NODES);
  gemm_mfma<1, false><<<gemmBlocks, 256, 0, stream>>>(hA, nullptr, wt + 7 * 16384, nullptr, nullptr, Bb, N_NODES);
  // ---- edge scores (pos + neg fused)
  edge_score_fused<<<edgeBlocks, 256, 0, stream>>>(Ab, Bb, src, dst, nsrc, ndst, Wp2, bp2, out, N_EDGES);
}